// Round 3
// baseline (2775.006 us; speedup 1.0000x reference)
//
#include <hip/hip_runtime.h>
#include <math.h>

#define HEADS 4
#define HID 610
#define HIDP 640   // K-padded row stride for MFMA (mult of 32)
#define FIN 128
#define KER 50
#define NOUT 86
#define NEG_SLOPE 0.2f

#define Y1S 616    // y1 LDS row stride (ushorts): 308 words, %32=20 -> 2-way banks, no swizzle
#define ZSS 520    // z LDS row stride (ushorts): 260 words, %32=4 -> 2-way banks

typedef short bf8_t __attribute__((ext_vector_type(8)));  // 8 bf16 (4 VGPRs)
typedef float f4_t __attribute__((ext_vector_type(4)));   // MFMA C/D

__device__ __forceinline__ ushort f2bf(float f) {  // RNE fp32->bf16
    unsigned u = __float_as_uint(f);
    unsigned r = (u + 0x7FFFu + ((u >> 16) & 1u)) >> 16;
    return (ushort)r;
}
__device__ __forceinline__ ushort f2bf_t(float f) {  // truncating split-hi (residual goes to lo)
    return (ushort)(__float_as_uint(f) >> 16);
}
__device__ __forceinline__ float bf2f(ushort b) { return __uint_as_float(((unsigned)b) << 16); }

// ---------------- utility ----------------
__global__ void fill_val(float* __restrict__ p, float v, long n) {
    long i = (long)blockIdx.x * blockDim.x + threadIdx.x;
    if (i < n) p[i] = v;
}

__global__ void copy_int(const int* __restrict__ a, int* __restrict__ b, int n) {
    int i = blockIdx.x * blockDim.x + threadIdx.x;
    if (i < n) b[i] = a[i];
}

// ---------------- edge sort by dst: histogram / scan / scatter ----------------
__global__ void hist_k(const int* __restrict__ ei, int* __restrict__ hist, int E) {
    int e = blockIdx.x * blockDim.x + threadIdx.x;
    if (e < E) atomicAdd(&hist[ei[E + e]], 1);
}

__global__ __launch_bounds__(1024) void scan_k(const int* __restrict__ hist,
                                               int* __restrict__ base, int Nn) {
    __shared__ int tmp[1024];
    __shared__ int carry;
    if (threadIdx.x == 0) carry = 0;
    __syncthreads();
    for (int c0 = 0; c0 < Nn; c0 += 1024) {
        int i = c0 + threadIdx.x;
        int v = (i < Nn) ? hist[i] : 0;
        tmp[threadIdx.x] = v;
        __syncthreads();
        for (int off = 1; off < 1024; off <<= 1) {
            int t = (threadIdx.x >= off) ? tmp[threadIdx.x - off] : 0;
            __syncthreads();
            tmp[threadIdx.x] += t;
            __syncthreads();
        }
        if (i < Nn) base[i] = carry + tmp[threadIdx.x] - v;  // exclusive
        __syncthreads();
        if (threadIdx.x == 1023) carry += tmp[1023];
        __syncthreads();
    }
    if (threadIdx.x == 0) base[Nn] = carry;
}

// scatter also records dst node and original edge id per sorted slot, so the fused
// edge kernel can process edges in dst-sorted order (dst-row gathers become L1/L2 hits)
__global__ void scatter_k(const int* __restrict__ ei, int* __restrict__ cursor,
                          int* __restrict__ esrc, int* __restrict__ edst,
                          int* __restrict__ eorg, int E) {
    int e = blockIdx.x * blockDim.x + threadIdx.x;
    if (e >= E) return;
    int d = ei[E + e];
    int pos = atomicAdd(&cursor[d], 1);
    esrc[pos] = ei[e];
    edst[pos] = d;
    eorg[pos] = e;
}

// ---------------- split fp32 -> bf16 hi/lo with K padding ----------------
__global__ void split_pad(const float* __restrict__ in, ushort* __restrict__ hi,
                          ushort* __restrict__ lo, int R, int K, int Kp) {
    long i = (long)blockIdx.x * blockDim.x + threadIdx.x;
    if (i >= (long)R * Kp) return;
    int r = (int)(i / Kp), c = (int)(i % Kp);
    float v = (c < K) ? in[(long)r * K + c] : 0.f;
    ushort h = f2bf(v);
    hi[i] = h;
    lo[i] = f2bf(v - bf2f(h));
}

// ---------------- Toeplitz weight-fragment tables for conv-as-MFMA ----------------
// 18 fragments of 512 ushorts each (frag f at T[f*512 + lane*8 + e]):
//   f = (hilo*2 + ch)*3 + c   (f<12): conv1, B[n,kk]=w4[ch*KER + (32c + k - n)]
//   f = 12 + hilo*3 + c       (f<18): conv2, B[n,kk]=w6[32c + k - n]
// with n = lane&15, k = (lane>>4)*8 + e  (16x16x32 B-fragment layout).
__global__ void build_toeplitz(const float* __restrict__ w4, const float* __restrict__ w6,
                               ushort* __restrict__ T) {
    int i = blockIdx.x * blockDim.x + threadIdx.x;
    if (i >= 18 * 512) return;
    int e = i & 7;
    int lane = (i >> 3) & 63;
    int f = i >> 9;
    int n = lane & 15;
    int k = ((lane >> 4) << 3) + e;
    float wv;
    int hilo;
    if (f < 12) {
        int c = f % 3, hc = f / 3;
        int ch = hc & 1;
        hilo = hc >> 1;
        int d = c * 32 + k - n;
        wv = (d >= 0 && d < KER) ? w4[ch * KER + d] : 0.f;
    } else {
        int r2 = f - 12;
        int c = r2 % 3;
        hilo = r2 / 3;
        int d = c * 32 + k - n;
        wv = (d >= 0 && d < KER) ? w6[d] : 0.f;
    }
    ushort h = f2bf(wv);
    T[i] = hilo ? f2bf(wv - bf2f(h)) : h;
}

// ---------------- split-bf16 MFMA GEMM: C[M,N] = A[M,Kp] * B[N,Kp]^T (+bias) ----------------
template <int AMODE, bool BIAS>
__global__ __launch_bounds__(256) void gemm_mfma(const float* __restrict__ A,
                                                 const ushort* __restrict__ Aghi,
                                                 const ushort* __restrict__ Aglo,
                                                 const ushort* __restrict__ Bghi,
                                                 const ushort* __restrict__ Bglo,
                                                 const float* __restrict__ bias,
                                                 float* __restrict__ C,
                                                 int M, int N, int Kp) {
    __shared__ __align__(16) ushort Ah[128 * 32];
    __shared__ __align__(16) ushort Al[128 * 32];
    __shared__ __align__(16) ushort Bh[128 * 32];
    __shared__ __align__(16) ushort Bl[128 * 32];
    int tid = threadIdx.x;
    int wave = tid >> 6, lane = tid & 63;
    int quad = lane >> 4, l16 = lane & 15;
    int wm = wave & 1, wn = wave >> 1;
    int row0 = blockIdx.y * 128, col0 = blockIdx.x * 128;

    float4 pa0[4];
    uint4 pah[2], pal[2], pbh[2], pbl[2];

    auto loadA = [&](int k0) {
        if (AMODE == 0) {
#pragma unroll
            for (int q = 0; q < 4; q++) {
                int p = tid + q * 256;
                int r = p >> 3, c4 = (p & 7) << 2;
                int gr = row0 + r;
                pa0[q] = (gr < M) ? *(const float4*)(A + (size_t)gr * Kp + k0 + c4)
                                  : make_float4(0.f, 0.f, 0.f, 0.f);
            }
        } else {
#pragma unroll
            for (int q = 0; q < 2; q++) {
                int p = tid + q * 256;
                int r = p >> 2, c = p & 3;
                int gr = row0 + r;
                if (gr < M) {
                    pah[q] = *(const uint4*)(Aghi + (size_t)gr * Kp + k0 + c * 8);
                    pal[q] = *(const uint4*)(Aglo + (size_t)gr * Kp + k0 + c * 8);
                } else {
                    pah[q] = make_uint4(0, 0, 0, 0);
                    pal[q] = make_uint4(0, 0, 0, 0);
                }
            }
        }
    };
    auto loadB = [&](int k0) {
#pragma unroll
        for (int q = 0; q < 2; q++) {
            int p = tid + q * 256;
            int r = p >> 2, c = p & 3;
            int gr = col0 + r;
            if (gr < N) {
                pbh[q] = *(const uint4*)(Bghi + (size_t)gr * Kp + k0 + c * 8);
                pbl[q] = *(const uint4*)(Bglo + (size_t)gr * Kp + k0 + c * 8);
            } else {
                pbh[q] = make_uint4(0, 0, 0, 0);
                pbl[q] = make_uint4(0, 0, 0, 0);
            }
        }
    };
    auto writeLDS = [&]() {
        if (AMODE == 0) {
#pragma unroll
            for (int q = 0; q < 4; q++) {
                int p = tid + q * 256;
                int r = p >> 3, m = p & 7;
                int pos = r * 32 + ((((m >> 1)) ^ ((r >> 1) & 3)) << 3) + ((m & 1) << 2);
                float4 v = pa0[q];
                ushort4 hv, lv;
                hv.x = f2bf(v.x); lv.x = f2bf(v.x - bf2f(hv.x));
                hv.y = f2bf(v.y); lv.y = f2bf(v.y - bf2f(hv.y));
                hv.z = f2bf(v.z); lv.z = f2bf(v.z - bf2f(hv.z));
                hv.w = f2bf(v.w); lv.w = f2bf(v.w - bf2f(hv.w));
                *(ushort4*)&Ah[pos] = hv;
                *(ushort4*)&Al[pos] = lv;
            }
        } else {
#pragma unroll
            for (int q = 0; q < 2; q++) {
                int p = tid + q * 256;
                int r = p >> 2, c = p & 3;
                int pos = r * 32 + ((c ^ ((r >> 1) & 3)) << 3);
                *(uint4*)&Ah[pos] = pah[q];
                *(uint4*)&Al[pos] = pal[q];
            }
        }
#pragma unroll
        for (int q = 0; q < 2; q++) {
            int p = tid + q * 256;
            int r = p >> 2, c = p & 3;
            int pos = r * 32 + ((c ^ ((r >> 1) & 3)) << 3);
            *(uint4*)&Bh[pos] = pbh[q];
            *(uint4*)&Bl[pos] = pbl[q];
        }
    };

    f4_t acc[4][4];
#pragma unroll
    for (int i = 0; i < 4; i++)
#pragma unroll
        for (int j = 0; j < 4; j++) acc[i][j] = (f4_t){0.f, 0.f, 0.f, 0.f};

    loadA(0);
    loadB(0);
    int sw = (quad ^ ((l16 >> 1) & 3)) << 3;
    for (int k0 = 0; k0 < Kp; k0 += 32) {
        __syncthreads();
        writeLDS();
        __syncthreads();
        if (k0 + 32 < Kp) {
            loadA(k0 + 32);
            loadB(k0 + 32);
        }
        bf8_t ah[4], al[4], bh[4], bl[4];
#pragma unroll
        for (int t = 0; t < 4; t++) {
            int ar = wm * 64 + t * 16 + l16;
            ah[t] = *(const bf8_t*)&Ah[ar * 32 + sw];
            al[t] = *(const bf8_t*)&Al[ar * 32 + sw];
            int br = wn * 64 + t * 16 + l16;
            bh[t] = *(const bf8_t*)&Bh[br * 32 + sw];
            bl[t] = *(const bf8_t*)&Bl[br * 32 + sw];
        }
#pragma unroll
        for (int i = 0; i < 4; i++)
#pragma unroll
            for (int j = 0; j < 4; j++) {
                acc[i][j] = __builtin_amdgcn_mfma_f32_16x16x32_bf16(ah[i], bh[j], acc[i][j], 0, 0, 0);
                acc[i][j] = __builtin_amdgcn_mfma_f32_16x16x32_bf16(al[i], bh[j], acc[i][j], 0, 0, 0);
                acc[i][j] = __builtin_amdgcn_mfma_f32_16x16x32_bf16(ah[i], bl[j], acc[i][j], 0, 0, 0);
            }
    }
    // epilogue: D row(m)=quad*4+reg, col(n)=lane&15
#pragma unroll
    for (int i = 0; i < 4; i++) {
#pragma unroll
        for (int r = 0; r < 4; r++) {
            int grow = row0 + wm * 64 + i * 16 + quad * 4 + r;
            if (grow >= M) continue;
#pragma unroll
            for (int j = 0; j < 4; j++) {
                int gcol = col0 + wn * 64 + j * 16 + l16;
                if (gcol >= N) continue;
                float v = acc[i][j][r];
                if (BIAS) v += bias[gcol];
                C[(size_t)grow * N + gcol] = v;
            }
        }
    }
}

// ---------------- attention dot products per node/head ----------------
__global__ __launch_bounds__(256) void attn_dots(const float* __restrict__ h,
                                                 const float* __restrict__ att_s,
                                                 const float* __restrict__ att_d,
                                                 float* __restrict__ a_src,
                                                 float* __restrict__ a_dst, int Nn) {
    int n = blockIdx.x;
    int head = threadIdx.x >> 6;
    int lane = threadIdx.x & 63;
    const float2* hr = (const float2*)(h + (long)n * (HEADS * HID) + head * HID);
    const float2* as = (const float2*)(att_s + head * HID);
    const float2* ad = (const float2*)(att_d + head * HID);
    float ss = 0.f, sd = 0.f;
    for (int d = lane; d < HID / 2; d += 64) {
        float2 hv = hr[d], av = as[d], dv = ad[d];
        ss += hv.x * av.x + hv.y * av.y;
        sd += hv.x * dv.x + hv.y * dv.y;
    }
    for (int off = 32; off > 0; off >>= 1) {
        ss += __shfl_down(ss, off);
        sd += __shfl_down(sd, off);
    }
    if (lane == 0) {
        a_src[n * HEADS + head] = ss;
        a_dst[n * HEADS + head] = sd;
    }
}

// ---------------- per-dst-node softmax + aggregation (atomic-free, CSR) ----------------
template <int OUTMODE>
__global__ __launch_bounds__(256) void node_aggregate(
    const float* __restrict__ h, const float* __restrict__ asrc,
    const float* __restrict__ adst, const int* __restrict__ base,
    const int* __restrict__ esrc, const float* __restrict__ bias,
    float* __restrict__ xout, ushort* __restrict__ xhi, ushort* __restrict__ xlo,
    int Nn) {
    int wave = threadIdx.x >> 6, lane = threadIdx.x & 63;
    int n = blockIdx.x * 4 + wave;
    if (n >= Nn) return;
    int b0 = base[n], deg = base[n + 1] - b0;
    float ad[HEADS];
#pragma unroll
    for (int hh = 0; hh < HEADS; hh++) ad[hh] = adst[n * HEADS + hh];
    float m[HEADS] = {-INFINITY, -INFINITY, -INFINITY, -INFINITY};
    for (int eb = 0; eb < deg; eb += 64) {
        int i = eb + lane;
        if (i < deg) {
            int s = esrc[b0 + i];
#pragma unroll
            for (int hh = 0; hh < HEADS; hh++) {
                float v = asrc[s * HEADS + hh] + ad[hh];
                v = v >= 0.f ? v : NEG_SLOPE * v;
                m[hh] = fmaxf(m[hh], v);
            }
        }
    }
#pragma unroll
    for (int off = 32; off > 0; off >>= 1)
#pragma unroll
        for (int hh = 0; hh < HEADS; hh++) m[hh] = fmaxf(m[hh], __shfl_xor(m[hh], off));
    float sden[HEADS] = {0.f, 0.f, 0.f, 0.f};
    for (int eb = 0; eb < deg; eb += 64) {
        int i = eb + lane;
        if (i < deg) {
            int s = esrc[b0 + i];
#pragma unroll
            for (int hh = 0; hh < HEADS; hh++) {
                float v = asrc[s * HEADS + hh] + ad[hh];
                v = v >= 0.f ? v : NEG_SLOPE * v;
                sden[hh] += expf(v - m[hh]);
            }
        }
    }
#pragma unroll
    for (int off = 32; off > 0; off >>= 1)
#pragma unroll
        for (int hh = 0; hh < HEADS; hh++) sden[hh] += __shfl_xor(sden[hh], off);
    float inv[HEADS];
#pragma unroll
    for (int hh = 0; hh < HEADS; hh++) inv[hh] = 0.25f / (sden[hh] + 1e-16f);
    float acc0[10] = {}, acc1[10] = {}, acc2[10] = {}, acc3[10] = {};
    for (int eb = 0; eb < deg; eb += 64) {
        int i = eb + lane;
        int sreg = 0;
        float coef[HEADS] = {0.f, 0.f, 0.f, 0.f};
        if (i < deg) {
            sreg = esrc[b0 + i];
#pragma unroll
            for (int hh = 0; hh < HEADS; hh++) {
                float v = asrc[sreg * HEADS + hh] + ad[hh];
                v = v >= 0.f ? v : NEG_SLOPE * v;
                coef[hh] = expf(v - m[hh]) * inv[hh];
            }
        }
        int cnt = deg - eb < 64 ? deg - eb : 64;
        for (int j = 0; j < cnt; j++) {
            int s = __shfl(sreg, j);
            float c0 = __shfl(coef[0], j), c1 = __shfl(coef[1], j);
            float c2 = __shfl(coef[2], j), c3 = __shfl(coef[3], j);
            const float* hr = h + (size_t)s * (HEADS * HID);
#pragma unroll
            for (int t = 0; t < 10; t++) {
                int d = lane + t * 64;
                if (d < HID) {
                    acc0[t] = fmaf(c0, hr[d], acc0[t]);
                    acc1[t] = fmaf(c1, hr[HID + d], acc1[t]);
                    acc2[t] = fmaf(c2, hr[2 * HID + d], acc2[t]);
                    acc3[t] = fmaf(c3, hr[3 * HID + d], acc3[t]);
                }
            }
        }
    }
#pragma unroll
    for (int t = 0; t < 10; t++) {
        int d = lane + t * 64;
        if (d < HID) {
            float v = acc0[t] + acc1[t] + acc2[t] + acc3[t] + bias[d];
            v = v > 0.f ? v : 0.f;
            if (OUTMODE == 0) {
                xout[(size_t)n * HIDP + d] = v;
            } else {
                ushort hv = f2bf(v);
                xhi[(size_t)n * HIDP + d] = hv;
                xlo[(size_t)n * HIDP + d] = f2bf(v - bf2f(hv));
            }
        }
    }
    for (int d = HID + lane; d < HIDP; d += 64) {
        if (OUTMODE == 0) {
            xout[(size_t)n * HIDP + d] = 0.f;
        } else {
            xhi[(size_t)n * HIDP + d] = 0;
            xlo[(size_t)n * HIDP + d] = 0;
        }
    }
}

// ---------------- fused edge pipeline via MFMA, 16 edges/block, dst-sorted order ------
// 4 waves split work as (p = j-block parity, half = tile range). 39.4KB LDS -> 4
// blocks/CU -> 16 waves/CU (2x latency hiding vs 32-edge version). Edges processed in
// dst-sorted order (esrc/edst/eorg), so the ~16 dst rows per block collapse to ~3-4
// distinct rows -> L1/L2 hits on half the gathers. Output scattered via eorg.
// Band sparsity: c=2 Toeplitz chunk has one live tap (d=49) -> hi*hi MFMA only.
__global__ __launch_bounds__(256, 4) void edge_fused(
    const ushort* __restrict__ x2hi, const ushort* __restrict__ x2lo,
    const int* __restrict__ esrc, const int* __restrict__ edst,
    const int* __restrict__ eorg, const ushort* __restrict__ T,
    const float* __restrict__ b4, const float* __restrict__ b6,
    const ushort* __restrict__ w8hi, const ushort* __restrict__ w8lo,
    const float* __restrict__ b8, float* __restrict__ out, int E) {
    __shared__ __align__(16) ushort y1h[16 * Y1S];
    __shared__ __align__(16) ushort y1l[16 * Y1S];
    const int tid = threadIdx.x;
    const int wave = tid >> 6, lane = tid & 63;
    const int quad = lane >> 4, l16 = lane & 15;
    const int e0 = blockIdx.x * 16;
    const int p = wave & 1;    // j-block parity this wave owns
    const int half = wave >> 1;  // tile-range half this wave owns
    const int p16 = p * 16;

    int i = e0 + l16;
    if (i >= E) i = E - 1;
    const int s = esrc[i], d = edst[i];
    const ushort* psh = x2hi + (size_t)s * HIDP + quad * 8;  // src row hi
    const ushort* psl = x2lo + (size_t)s * HIDP + quad * 8;  // src row lo
    const ushort* pth = x2hi + (size_t)d * HIDP + quad * 8;  // dst row hi
    const ushort* ptl = x2lo + (size_t)d * HIDP + quad * 8;  // dst row lo

    // chunk m covers ushorts [p16+32m, p16+32m+32); tile t uses m=t,t+1,t+2.
    // chunk 19 is only ever used as c=2 (hi-only) -> skip its lo loads.
    bf8_t Wsh[8], Wsl[8], Wth[8], Wtl[8];
#define LDCH(slot, m)                                     \
    {                                                     \
        const int o_ = p16 + 32 * (m);                    \
        Wsh[slot] = *(const bf8_t*)(psh + o_);            \
        Wth[slot] = *(const bf8_t*)(pth + o_);            \
        if ((m) <= 18) {                                  \
            Wsl[slot] = *(const bf8_t*)(psl + o_);        \
            Wtl[slot] = *(const bf8_t*)(ptl + o_);        \
        }                                                 \
    }
    const int t0 = half * 9;  // conv1 tiles t0..t0+8, chunks t0..t0+10
#pragma unroll
    for (int m = 0; m < 7; m++) LDCH((t0 + m) & 7, t0 + m);

    // zero tail j in [576, Y1S): conv2 reads up to j=591; never written by conv1.
    for (int idx = tid; idx < 16 * (Y1S - 576); idx += 256) {
        int r = idx / (Y1S - 576);
        int j = 576 + (idx - r * (Y1S - 576));
        y1h[r * Y1S + j] = 0;
        y1l[r * Y1S + j] = 0;
    }

    // Toeplitz conv1 weight frags (loop-invariant). lo frags only needed for c<2.
    bf8_t B1h[2][3], B1l[2][2];
#pragma unroll
    for (int ch = 0; ch < 2; ch++) {
#pragma unroll
        for (int c = 0; c < 3; c++)
            B1h[ch][c] = *(const bf8_t*)&T[(ch * 3 + c) * 512 + lane * 8];
#pragma unroll
        for (int c = 0; c < 2; c++)
            B1l[ch][c] = *(const bf8_t*)&T[((2 + ch) * 3 + c) * 512 + lane * 8];
    }
    const float bb4 = b4[0], bb6 = b6[0];

    // ---- conv1: 9 tiles/wave, 14 MFMA + (early tiles) 4 prefetch loads per tile ----
#pragma unroll
    for (int tt = 0; tt < 9; tt++) {
        const int t = t0 + tt;
        if (tt <= 3) LDCH((t + 7) & 7, t + 7);
        const int c0 = t & 7, c1 = (t + 1) & 7, c2 = (t + 2) & 7;
        f4_t acc = {bb4, bb4, bb4, bb4};
        acc = __builtin_amdgcn_mfma_f32_16x16x32_bf16(Wsh[c0], B1h[0][0], acc, 0, 0, 0);
        acc = __builtin_amdgcn_mfma_f32_16x16x32_bf16(Wsl[c0], B1h[0][0], acc, 0, 0, 0);
        acc = __builtin_amdgcn_mfma_f32_16x16x32_bf16(Wsh[c0], B1l[0][0], acc, 0, 0, 0);
        acc = __builtin_amdgcn_mfma_f32_16x16x32_bf16(Wth[c0], B1h[1][0], acc, 0, 0, 0);
        acc = __builtin_amdgcn_mfma_f32_16x16x32_bf16(Wtl[c0], B1h[1][0], acc, 0, 0, 0);
        acc = __builtin_amdgcn_mfma_f32_16x16x32_bf16(Wth[c0], B1l[1][0], acc, 0, 0, 0);
        acc = __builtin_amdgcn_mfma_f32_16x16x32_bf16(Wsh[c1], B1h[0][1], acc, 0, 0, 0);
        acc = __builtin_amdgcn_mfma_f32_16x16x32_bf16(Wsl[c1], B1h[0][1], acc, 0, 0, 0);
        acc = __builtin_amdgcn_mfma_f32_16x16x32_bf16(Wsh[c1], B1l[0][1], acc, 0, 0, 0);
        acc = __builtin_amdgcn_mfma_f32_16x16x32_bf16(Wth[c1], B1h[1][1], acc, 0, 0, 0);
        acc = __builtin_amdgcn_mfma_f32_16x16x32_bf16(Wtl[c1], B1h[1][1], acc, 0, 0, 0);
        acc = __builtin_amdgcn_mfma_f32_16x16x32_bf16(Wth[c1], B1l[1][1], acc, 0, 0, 0);
        acc = __builtin_amdgcn_mfma_f32_16x16x32_bf16(Wsh[c2], B1h[0][2], acc, 0, 0, 0);
        acc = __builtin_amdgcn_mfma_f32_16x16x32_bf16(Wth[c2], B1h[1][2], acc, 0, 0, 0);
        const int j0 = p16 + 32 * t;
#pragma unroll
        for (int r = 0; r < 4; r++) {
            int e_ = quad * 4 + r;
            int pos = e_ * Y1S + j0 + l16;
            float v = acc[r];
            v = v > 0.f ? v : 0.f;
            ushort hh = f2bf_t(v);
            y1h[pos] = hh;
            y1l[pos] = f2bf(v - bf2f(hh));
        }
    }
    __syncthreads();

    // ---- conv2: 8 tiles/wave, sliding LDS chunk ring (2 new ds_reads/tile) ----
    bf8_t B2h[3], B2l[2];
#pragma unroll
    for (int c = 0; c < 3; c++) B2h[c] = *(const bf8_t*)&T[(12 + c) * 512 + lane * 8];
#pragma unroll
    for (int c = 0; c < 2; c++) B2l[c] = *(const bf8_t*)&T[(15 + c) * 512 + lane * 8];
    const int arow1 = l16 * Y1S + quad * 8;
    bf8_t Yh[4], Yl[4];
#define LDY(slot, m)                                          \
    {                                                         \
        const int o_ = arow1 + p16 + 32 * (m);                \
        Yh[slot] = *(const bf8_t*)&y1h[o_];                   \
        if ((m) <= 16) Yl[slot] = *(const bf8_t*)&y1l[o_];    \
    }
    const int t0b = half * 8;  // conv2 tiles t0b..t0b+7, chunks t0b..t0b+9
#pragma unroll
    for (int m = 0; m < 3; m++) LDY((t0b + m) & 3, t0b + m);
    f4_t zac[8];
#pragma unroll
    for (int tt = 0; tt < 8; tt++) {
        const int t = t0b + tt;
        if (tt <= 6) LDY((t + 3) & 3, t + 3);
        const int c0 = t & 3, c1 = (t + 1) & 3, c2 = (t + 2) & 3;
        f4_t acc = {bb6, bb6, bb6, bb6};
        acc = __builtin_amdgcn_mfma_f32_16x16x32_bf16(Yh[c0], B2h[0], acc, 0, 0, 0);
        acc = __builtin_amdgcn_mfma_f32_16x16x32_bf16(Yl[c0], B2h[0], acc, 0, 0, 0);
        acc = __builtin_amdgcn_mfma_f32_16x16x32_bf16(Yh[c0], B2l[0], acc, 0, 0, 0);
        acc = __builtin_amdgcn_mfma_f32_16x16x32_bf16(Yh[c1], B2h[1], acc, 0, 0, 0);
        acc = __builtin_amdgcn_mfma_f32_16x16x32_bf16(Yl[c1], B2h[1], acc, 0, 0, 0);
        acc = __builtin_amdgcn_mfma_f32_16x16x32_bf16(Yh[c1], B2l[1], acc, 0, 0, 0);
        acc = __builtin_amdgcn_mfma_f32_16x16x32_bf16(Yh[c2], B2h[2], acc, 0, 0, 0);
#pragma unroll
        for (int r = 0; r < 4; r++) {
            float v = acc[r];
            zac[tt][r] = v > 0.f ? v : 0.f;
        }
    }
    __syncthreads();  // all conv2 reads of y1 complete before overwrite

    // ---- write z (bf16 hi/lo) into LDS (reusing y1 space), stride ZSS ----
#pragma unroll
    for (int tt = 0; tt < 8; tt++) {
        const int j02 = p16 + 32 * (t0b + tt);
#pragma unroll
        for (int r = 0; r < 4; r++) {
            int e_ = quad * 4 + r;
            int pos = e_ * ZSS + j02 + l16;
            float v = zac[tt][r];
            ushort hh = f2bf_t(v);
            y1h[pos] = hh;
            y1l[pos] = f2bf(v - bf2f(hh));
        }
    }
    __syncthreads();

    // ---- final linear: out = z @ w8^T + b8 (6 col-tiles of 16 over 4 waves) ----
#pragma unroll
    for (int it = 0; it < 2; it++) {
        const int nt = wave + it * 4;
        if (nt < 6) {
            const int col = nt * 16 + l16;
            const int wrow = col < NOUT ? col : 0;
            const float bias = col < NOUT ? b8[col] : 0.f;
            f4_t acc = {bias, bias, bias, bias};
            const int arow = l16 * ZSS + quad * 8;
            const ushort* wph = w8hi + (size_t)wrow * 512 + quad * 8;
            const ushort* wpl = w8lo + (size_t)wrow * 512 + quad * 8;
#pragma unroll
            for (int c = 0; c < 16; c++) {
                bf8_t zh = *(const bf8_t*)&y1h[arow + c * 32];
                bf8_t zl = *(const bf8_t*)&y1l[arow + c * 32];
                bf8_t wh = *(const bf8_t*)(wph + c * 32);
                bf8_t wl = *(const bf8_t*)(wpl + c * 32);
                acc = __builtin_amdgcn_mfma_f32_16x16x32_bf16(zh, wh, acc, 0, 0, 0);
                acc = __builtin_amdgcn_mfma_f32_16x16x32_bf16(zl, wh, acc, 0, 0, 0);
                acc = __builtin_amdgcn_mfma_f32_16x16x32_bf16(zh, wl, acc, 0, 0, 0);
            }
            if (col < NOUT) {
#pragma unroll
                for (int r = 0; r < 4; r++) {
                    int er = e0 + quad * 4 + r;
                    if (er < E) out[(size_t)eorg[er] * NOUT + col] = acc[r];
                }
            }
        }
    }
#undef LDCH
#undef LDY
}

extern "C" void kernel_launch(void* const* d_in, const int* in_sizes, int n_in,
                              void* d_out, int out_size, void* d_ws, size_t ws_size,
                              hipStream_t stream) {
    const float* x = (const float*)d_in[0];
    const int* ei = (const int*)d_in[1];  // int32
    const float* w0 = (const float*)d_in[2];
    const float* b0 = (const float*)d_in[3];
    const float* att_s0 = (const float*)d_in[4];
    const float* att_d0 = (const float*)d_in[5];
    const float* w2 = (const float*)d_in[6];
    const float* b2 = (const float*)d_in[7];
    const float* att_s1 = (const float*)d_in[8];
    const float* att_d1 = (const float*)d_in[9];
    const float* w4 = (const float*)d_in[10];
    const float* b4 = (const float*)d_in[11];
    const float* w6 = (const float*)d_in[12];
    const float* b6 = (const float*)d_in[13];
    const float* w8 = (const float*)d_in[14];
    const float* b8 = (const float*)d_in[15];
    float* out = (float*)d_out;

    const int Nn = in_sizes[0] / FIN;  // 20000
    const int E = in_sizes[1] / 2;     // 100000
    const int HD = HEADS * HID;        // 2440

    // ---- workspace layout (floats); watermark stays under the proven-safe 256.09MB ----
    float* ws = (float*)d_ws;
    size_t o = 0;
    float* buf1 = ws + o; o += (size_t)Nn * HIDP;  // x1/x2 as bf16 hi/lo
    ushort* x1hi = (ushort*)buf1;                  // Nn*HIDP bf16 (hi)
    ushort* x1lo = x1hi + (size_t)Nn * HIDP;       // Nn*HIDP bf16 (lo)
    ushort* w8hi = (ushort*)(ws + o);
    ushort* w8lo = w8hi + (size_t)NOUT * 512; o += (size_t)NOUT * 512;
    int* base = (int*)(ws + o); o += (size_t)Nn + 4;
    int* cursor = (int*)(ws + o); o += (size_t)Nn;  // also hist
    int* esrc = (int*)(ws + o); o += (size_t)E;
    int* edst = (int*)(ws + o); o += (size_t)E;
    int* eorg = (int*)(ws + o); o += (size_t)E;
    float* asrc = ws + o; o += (size_t)Nn * HEADS;
    float* adst = ws + o; o += (size_t)Nn * HEADS;
    ushort* w0hi = (ushort*)(ws + o);
    ushort* w0lo = w0hi + (size_t)HD * FIN; o += (size_t)HD * FIN;
    ushort* w2hi = (ushort*)(ws + o);
    ushort* w2lo = w2hi + (size_t)HD * HIDP; o += (size_t)HD * HIDP;
    float* h = ws + o;  // Nn*2440 fp32

    int edgeGrid = (E + 255) / 256;
    int nodeWaveGrid = (Nn + 3) / 4;
    int fusedGrid = (E + 15) / 16;
    dim3 gGemmL((HD + 127) / 128, (Nn + 127) / 128);   // 20 x 157

    // ---- one-time: weight split + edge sort by dst ----
    split_pad<<<((HD * FIN) + 255) / 256, 256, 0, stream>>>(w0, w0hi, w0lo, HD, FIN, FIN);
    split_pad<<<((HD * HIDP) + 255) / 256, 256, 0, stream>>>(w2, w2hi, w2lo, HD, HID, HIDP);
    split_pad<<<((NOUT * 512) + 255) / 256, 256, 0, stream>>>(w8, w8hi, w8lo, NOUT, 512, 512);
    fill_val<<<(Nn + 255) / 256, 256, 0, stream>>>((float*)cursor, 0.f, Nn);  // hist=0
    hist_k<<<edgeGrid, 256, 0, stream>>>(ei, cursor, E);
    scan_k<<<1, 1024, 0, stream>>>(cursor, base, Nn);
    copy_int<<<(Nn + 255) / 256, 256, 0, stream>>>(base, cursor, Nn);
    scatter_k<<<edgeGrid, 256, 0, stream>>>(ei, cursor, esrc, edst, eorg, E);

    // ---------- GAT layer 1 ----------
    gemm_mfma<0, false><<<gGemmL, 256, 0, stream>>>(x, nullptr, nullptr, w0hi, w0lo, nullptr,
                                                    h, Nn, HD, FIN);
    // w0hi slot is dead after gemm L1 -> reuse it for the Toeplitz frag table (18*512 ushorts)
    build_toeplitz<<<(18 * 512 + 255) / 256, 256, 0, stream>>>(w4, w6, w0hi);
    attn_dots<<<Nn, 256, 0, stream>>>(h, att_s0, att_d0, asrc, adst, Nn);
    node_aggregate<1><<<nodeWaveGrid, 256, 0, stream>>>(h, asrc, adst, base, esrc, b0,
                                                        nullptr, x1hi, x1lo, Nn);

    // ---------- GAT layer 2 (A pre-split: no conversion VALU in hot loop) ----------
    gemm_mfma<1, false><<<gGemmL, 256, 0, stream>>>(nullptr, x1hi, x1lo, w2hi, w2lo, nullptr,
                                                    h, Nn, HD, HIDP);
    attn_dots<<<Nn, 256, 0, stream>>>(h, att_s1, att_d1, asrc, adst, Nn);
    // layer-2 output written directly as bf16 hi/lo (consumed by MFMA conv)
    node_aggregate<1><<<nodeWaveGrid, 256, 0, stream>>>(h, asrc, adst, base, esrc, b2,
                                                        nullptr, x1hi, x1lo, Nn);

    // ---------- fused edge conv1+conv2+final linear (MFMA, 16 edges/block, dst-sorted) ----
    edge_fused<<<fusedGrid, 256, 0, stream>>>(x1hi, x1lo, esrc, edst, eorg, w0hi, b4, b6,
                                              w8hi, w8lo, b8, out, E);
}

// Round 4
// 1209.233 us; speedup vs baseline: 2.2948x; 2.2948x over previous
//
#include <hip/hip_runtime.h>
#include <math.h>

#define HEADS 4
#define HID 610
#define HIDP 640   // K-padded row stride for MFMA (mult of 32)
#define FIN 128
#define KER 50
#define NOUT 86
#define NEG_SLOPE 0.2f

#define Y1S 616    // y1 LDS row stride (ushorts): 308 words, %32=20 -> 2-way banks, no swizzle
#define ZSS 520    // z LDS row stride (ushorts): 260 words, %32=4 -> 2-way banks

typedef short bf8_t __attribute__((ext_vector_type(8)));  // 8 bf16 (4 VGPRs)
typedef float f4_t __attribute__((ext_vector_type(4)));   // MFMA C/D

__device__ __forceinline__ ushort f2bf(float f) {  // RNE fp32->bf16
    unsigned u = __float_as_uint(f);
    unsigned r = (u + 0x7FFFu + ((u >> 16) & 1u)) >> 16;
    return (ushort)r;
}
__device__ __forceinline__ ushort f2bf_t(float f) {  // truncating split-hi (residual goes to lo)
    return (ushort)(__float_as_uint(f) >> 16);
}
__device__ __forceinline__ float bf2f(ushort b) { return __uint_as_float(((unsigned)b) << 16); }

// ---------------- utility ----------------
__global__ void fill_val(float* __restrict__ p, float v, long n) {
    long i = (long)blockIdx.x * blockDim.x + threadIdx.x;
    if (i < n) p[i] = v;
}

__global__ void copy_int(const int* __restrict__ a, int* __restrict__ b, int n) {
    int i = blockIdx.x * blockDim.x + threadIdx.x;
    if (i < n) b[i] = a[i];
}

// ---------------- edge sort by dst: histogram / scan / scatter ----------------
__global__ void hist_k(const int* __restrict__ ei, int* __restrict__ hist, int E) {
    int e = blockIdx.x * blockDim.x + threadIdx.x;
    if (e < E) atomicAdd(&hist[ei[E + e]], 1);
}

__global__ __launch_bounds__(1024) void scan_k(const int* __restrict__ hist,
                                               int* __restrict__ base, int Nn) {
    __shared__ int tmp[1024];
    __shared__ int carry;
    if (threadIdx.x == 0) carry = 0;
    __syncthreads();
    for (int c0 = 0; c0 < Nn; c0 += 1024) {
        int i = c0 + threadIdx.x;
        int v = (i < Nn) ? hist[i] : 0;
        tmp[threadIdx.x] = v;
        __syncthreads();
        for (int off = 1; off < 1024; off <<= 1) {
            int t = (threadIdx.x >= off) ? tmp[threadIdx.x - off] : 0;
            __syncthreads();
            tmp[threadIdx.x] += t;
            __syncthreads();
        }
        if (i < Nn) base[i] = carry + tmp[threadIdx.x] - v;  // exclusive
        __syncthreads();
        if (threadIdx.x == 1023) carry += tmp[1023];
        __syncthreads();
    }
    if (threadIdx.x == 0) base[Nn] = carry;
}

// scatter also records dst node and original edge id per sorted slot, so the fused
// edge kernel can process edges in dst-sorted order (dst-row gathers become L1/L2 hits)
__global__ void scatter_k(const int* __restrict__ ei, int* __restrict__ cursor,
                          int* __restrict__ esrc, int* __restrict__ edst,
                          int* __restrict__ eorg, int E) {
    int e = blockIdx.x * blockDim.x + threadIdx.x;
    if (e >= E) return;
    int d = ei[E + e];
    int pos = atomicAdd(&cursor[d], 1);
    esrc[pos] = ei[e];
    edst[pos] = d;
    eorg[pos] = e;
}

// ---------------- split fp32 -> bf16 hi/lo with K padding ----------------
__global__ void split_pad(const float* __restrict__ in, ushort* __restrict__ hi,
                          ushort* __restrict__ lo, int R, int K, int Kp) {
    long i = (long)blockIdx.x * blockDim.x + threadIdx.x;
    if (i >= (long)R * Kp) return;
    int r = (int)(i / Kp), c = (int)(i % Kp);
    float v = (c < K) ? in[(long)r * K + c] : 0.f;
    ushort h = f2bf(v);
    hi[i] = h;
    lo[i] = f2bf(v - bf2f(h));
}

// ---------------- Toeplitz weight-fragment tables for conv-as-MFMA ----------------
// 18 fragments of 512 ushorts each (frag f at T[f*512 + lane*8 + e]):
//   f = (hilo*2 + ch)*3 + c   (f<12): conv1, B[n,kk]=w4[ch*KER + (32c + k - n)]
//   f = 12 + hilo*3 + c       (f<18): conv2, B[n,kk]=w6[32c + k - n]
// with n = lane&15, k = (lane>>4)*8 + e  (16x16x32 B-fragment layout).
__global__ void build_toeplitz(const float* __restrict__ w4, const float* __restrict__ w6,
                               ushort* __restrict__ T) {
    int i = blockIdx.x * blockDim.x + threadIdx.x;
    if (i >= 18 * 512) return;
    int e = i & 7;
    int lane = (i >> 3) & 63;
    int f = i >> 9;
    int n = lane & 15;
    int k = ((lane >> 4) << 3) + e;
    float wv;
    int hilo;
    if (f < 12) {
        int c = f % 3, hc = f / 3;
        int ch = hc & 1;
        hilo = hc >> 1;
        int d = c * 32 + k - n;
        wv = (d >= 0 && d < KER) ? w4[ch * KER + d] : 0.f;
    } else {
        int r2 = f - 12;
        int c = r2 % 3;
        hilo = r2 / 3;
        int d = c * 32 + k - n;
        wv = (d >= 0 && d < KER) ? w6[d] : 0.f;
    }
    ushort h = f2bf(wv);
    T[i] = hilo ? f2bf(wv - bf2f(h)) : h;
}

// ---------------- split-bf16 MFMA GEMM: C[M,N] = A[M,Kp] * B[N,Kp]^T (+bias) ----------------
template <int AMODE, bool BIAS>
__global__ __launch_bounds__(256) void gemm_mfma(const float* __restrict__ A,
                                                 const ushort* __restrict__ Aghi,
                                                 const ushort* __restrict__ Aglo,
                                                 const ushort* __restrict__ Bghi,
                                                 const ushort* __restrict__ Bglo,
                                                 const float* __restrict__ bias,
                                                 float* __restrict__ C,
                                                 int M, int N, int Kp) {
    __shared__ __align__(16) ushort Ah[128 * 32];
    __shared__ __align__(16) ushort Al[128 * 32];
    __shared__ __align__(16) ushort Bh[128 * 32];
    __shared__ __align__(16) ushort Bl[128 * 32];
    int tid = threadIdx.x;
    int wave = tid >> 6, lane = tid & 63;
    int quad = lane >> 4, l16 = lane & 15;
    int wm = wave & 1, wn = wave >> 1;
    int row0 = blockIdx.y * 128, col0 = blockIdx.x * 128;

    float4 pa0[4];
    uint4 pah[2], pal[2], pbh[2], pbl[2];

    auto loadA = [&](int k0) {
        if (AMODE == 0) {
#pragma unroll
            for (int q = 0; q < 4; q++) {
                int p = tid + q * 256;
                int r = p >> 3, c4 = (p & 7) << 2;
                int gr = row0 + r;
                pa0[q] = (gr < M) ? *(const float4*)(A + (size_t)gr * Kp + k0 + c4)
                                  : make_float4(0.f, 0.f, 0.f, 0.f);
            }
        } else {
#pragma unroll
            for (int q = 0; q < 2; q++) {
                int p = tid + q * 256;
                int r = p >> 2, c = p & 3;
                int gr = row0 + r;
                if (gr < M) {
                    pah[q] = *(const uint4*)(Aghi + (size_t)gr * Kp + k0 + c * 8);
                    pal[q] = *(const uint4*)(Aglo + (size_t)gr * Kp + k0 + c * 8);
                } else {
                    pah[q] = make_uint4(0, 0, 0, 0);
                    pal[q] = make_uint4(0, 0, 0, 0);
                }
            }
        }
    };
    auto loadB = [&](int k0) {
#pragma unroll
        for (int q = 0; q < 2; q++) {
            int p = tid + q * 256;
            int r = p >> 2, c = p & 3;
            int gr = col0 + r;
            if (gr < N) {
                pbh[q] = *(const uint4*)(Bghi + (size_t)gr * Kp + k0 + c * 8);
                pbl[q] = *(const uint4*)(Bglo + (size_t)gr * Kp + k0 + c * 8);
            } else {
                pbh[q] = make_uint4(0, 0, 0, 0);
                pbl[q] = make_uint4(0, 0, 0, 0);
            }
        }
    };
    auto writeLDS = [&]() {
        if (AMODE == 0) {
#pragma unroll
            for (int q = 0; q < 4; q++) {
                int p = tid + q * 256;
                int r = p >> 3, m = p & 7;
                int pos = r * 32 + ((((m >> 1)) ^ ((r >> 1) & 3)) << 3) + ((m & 1) << 2);
                float4 v = pa0[q];
                ushort4 hv, lv;
                hv.x = f2bf(v.x); lv.x = f2bf(v.x - bf2f(hv.x));
                hv.y = f2bf(v.y); lv.y = f2bf(v.y - bf2f(hv.y));
                hv.z = f2bf(v.z); lv.z = f2bf(v.z - bf2f(hv.z));
                hv.w = f2bf(v.w); lv.w = f2bf(v.w - bf2f(hv.w));
                *(ushort4*)&Ah[pos] = hv;
                *(ushort4*)&Al[pos] = lv;
            }
        } else {
#pragma unroll
            for (int q = 0; q < 2; q++) {
                int p = tid + q * 256;
                int r = p >> 2, c = p & 3;
                int pos = r * 32 + ((c ^ ((r >> 1) & 3)) << 3);
                *(uint4*)&Ah[pos] = pah[q];
                *(uint4*)&Al[pos] = pal[q];
            }
        }
#pragma unroll
        for (int q = 0; q < 2; q++) {
            int p = tid + q * 256;
            int r = p >> 2, c = p & 3;
            int pos = r * 32 + ((c ^ ((r >> 1) & 3)) << 3);
            *(uint4*)&Bh[pos] = pbh[q];
            *(uint4*)&Bl[pos] = pbl[q];
        }
    };

    f4_t acc[4][4];
#pragma unroll
    for (int i = 0; i < 4; i++)
#pragma unroll
        for (int j = 0; j < 4; j++) acc[i][j] = (f4_t){0.f, 0.f, 0.f, 0.f};

    loadA(0);
    loadB(0);
    int sw = (quad ^ ((l16 >> 1) & 3)) << 3;
    for (int k0 = 0; k0 < Kp; k0 += 32) {
        __syncthreads();
        writeLDS();
        __syncthreads();
        if (k0 + 32 < Kp) {
            loadA(k0 + 32);
            loadB(k0 + 32);
        }
        bf8_t ah[4], al[4], bh[4], bl[4];
#pragma unroll
        for (int t = 0; t < 4; t++) {
            int ar = wm * 64 + t * 16 + l16;
            ah[t] = *(const bf8_t*)&Ah[ar * 32 + sw];
            al[t] = *(const bf8_t*)&Al[ar * 32 + sw];
            int br = wn * 64 + t * 16 + l16;
            bh[t] = *(const bf8_t*)&Bh[br * 32 + sw];
            bl[t] = *(const bf8_t*)&Bl[br * 32 + sw];
        }
#pragma unroll
        for (int i = 0; i < 4; i++)
#pragma unroll
            for (int j = 0; j < 4; j++) {
                acc[i][j] = __builtin_amdgcn_mfma_f32_16x16x32_bf16(ah[i], bh[j], acc[i][j], 0, 0, 0);
                acc[i][j] = __builtin_amdgcn_mfma_f32_16x16x32_bf16(al[i], bh[j], acc[i][j], 0, 0, 0);
                acc[i][j] = __builtin_amdgcn_mfma_f32_16x16x32_bf16(ah[i], bl[j], acc[i][j], 0, 0, 0);
            }
    }
    // epilogue: D row(m)=quad*4+reg, col(n)=lane&15
#pragma unroll
    for (int i = 0; i < 4; i++) {
#pragma unroll
        for (int r = 0; r < 4; r++) {
            int grow = row0 + wm * 64 + i * 16 + quad * 4 + r;
            if (grow >= M) continue;
#pragma unroll
            for (int j = 0; j < 4; j++) {
                int gcol = col0 + wn * 64 + j * 16 + l16;
                if (gcol >= N) continue;
                float v = acc[i][j][r];
                if (BIAS) v += bias[gcol];
                C[(size_t)grow * N + gcol] = v;
            }
        }
    }
}

// ---------------- attention dot products per node/head ----------------
__global__ __launch_bounds__(256) void attn_dots(const float* __restrict__ h,
                                                 const float* __restrict__ att_s,
                                                 const float* __restrict__ att_d,
                                                 float* __restrict__ a_src,
                                                 float* __restrict__ a_dst, int Nn) {
    int n = blockIdx.x;
    int head = threadIdx.x >> 6;
    int lane = threadIdx.x & 63;
    const float2* hr = (const float2*)(h + (long)n * (HEADS * HID) + head * HID);
    const float2* as = (const float2*)(att_s + head * HID);
    const float2* ad = (const float2*)(att_d + head * HID);
    float ss = 0.f, sd = 0.f;
    for (int d = lane; d < HID / 2; d += 64) {
        float2 hv = hr[d], av = as[d], dv = ad[d];
        ss += hv.x * av.x + hv.y * av.y;
        sd += hv.x * dv.x + hv.y * dv.y;
    }
    for (int off = 32; off > 0; off >>= 1) {
        ss += __shfl_down(ss, off);
        sd += __shfl_down(sd, off);
    }
    if (lane == 0) {
        a_src[n * HEADS + head] = ss;
        a_dst[n * HEADS + head] = sd;
    }
}

// ---------------- per-dst-node softmax + aggregation (atomic-free, CSR) ----------------
template <int OUTMODE>
__global__ __launch_bounds__(256) void node_aggregate(
    const float* __restrict__ h, const float* __restrict__ asrc,
    const float* __restrict__ adst, const int* __restrict__ base,
    const int* __restrict__ esrc, const float* __restrict__ bias,
    float* __restrict__ xout, ushort* __restrict__ xhi, ushort* __restrict__ xlo,
    int Nn) {
    int wave = threadIdx.x >> 6, lane = threadIdx.x & 63;
    int n = blockIdx.x * 4 + wave;
    if (n >= Nn) return;
    int b0 = base[n], deg = base[n + 1] - b0;
    float ad[HEADS];
#pragma unroll
    for (int hh = 0; hh < HEADS; hh++) ad[hh] = adst[n * HEADS + hh];
    float m[HEADS] = {-INFINITY, -INFINITY, -INFINITY, -INFINITY};
    for (int eb = 0; eb < deg; eb += 64) {
        int i = eb + lane;
        if (i < deg) {
            int s = esrc[b0 + i];
#pragma unroll
            for (int hh = 0; hh < HEADS; hh++) {
                float v = asrc[s * HEADS + hh] + ad[hh];
                v = v >= 0.f ? v : NEG_SLOPE * v;
                m[hh] = fmaxf(m[hh], v);
            }
        }
    }
#pragma unroll
    for (int off = 32; off > 0; off >>= 1)
#pragma unroll
        for (int hh = 0; hh < HEADS; hh++) m[hh] = fmaxf(m[hh], __shfl_xor(m[hh], off));
    float sden[HEADS] = {0.f, 0.f, 0.f, 0.f};
    for (int eb = 0; eb < deg; eb += 64) {
        int i = eb + lane;
        if (i < deg) {
            int s = esrc[b0 + i];
#pragma unroll
            for (int hh = 0; hh < HEADS; hh++) {
                float v = asrc[s * HEADS + hh] + ad[hh];
                v = v >= 0.f ? v : NEG_SLOPE * v;
                sden[hh] += expf(v - m[hh]);
            }
        }
    }
#pragma unroll
    for (int off = 32; off > 0; off >>= 1)
#pragma unroll
        for (int hh = 0; hh < HEADS; hh++) sden[hh] += __shfl_xor(sden[hh], off);
    float inv[HEADS];
#pragma unroll
    for (int hh = 0; hh < HEADS; hh++) inv[hh] = 0.25f / (sden[hh] + 1e-16f);
    float acc0[10] = {}, acc1[10] = {}, acc2[10] = {}, acc3[10] = {};
    for (int eb = 0; eb < deg; eb += 64) {
        int i = eb + lane;
        int sreg = 0;
        float coef[HEADS] = {0.f, 0.f, 0.f, 0.f};
        if (i < deg) {
            sreg = esrc[b0 + i];
#pragma unroll
            for (int hh = 0; hh < HEADS; hh++) {
                float v = asrc[sreg * HEADS + hh] + ad[hh];
                v = v >= 0.f ? v : NEG_SLOPE * v;
                coef[hh] = expf(v - m[hh]) * inv[hh];
            }
        }
        int cnt = deg - eb < 64 ? deg - eb : 64;
        for (int j = 0; j < cnt; j++) {
            int s = __shfl(sreg, j);
            float c0 = __shfl(coef[0], j), c1 = __shfl(coef[1], j);
            float c2 = __shfl(coef[2], j), c3 = __shfl(coef[3], j);
            const float* hr = h + (size_t)s * (HEADS * HID);
#pragma unroll
            for (int t = 0; t < 10; t++) {
                int d = lane + t * 64;
                if (d < HID) {
                    acc0[t] = fmaf(c0, hr[d], acc0[t]);
                    acc1[t] = fmaf(c1, hr[HID + d], acc1[t]);
                    acc2[t] = fmaf(c2, hr[2 * HID + d], acc2[t]);
                    acc3[t] = fmaf(c3, hr[3 * HID + d], acc3[t]);
                }
            }
        }
    }
#pragma unroll
    for (int t = 0; t < 10; t++) {
        int d = lane + t * 64;
        if (d < HID) {
            float v = acc0[t] + acc1[t] + acc2[t] + acc3[t] + bias[d];
            v = v > 0.f ? v : 0.f;
            if (OUTMODE == 0) {
                xout[(size_t)n * HIDP + d] = v;
            } else {
                ushort hv = f2bf(v);
                xhi[(size_t)n * HIDP + d] = hv;
                xlo[(size_t)n * HIDP + d] = f2bf(v - bf2f(hv));
            }
        }
    }
    for (int d = HID + lane; d < HIDP; d += 64) {
        if (OUTMODE == 0) {
            xout[(size_t)n * HIDP + d] = 0.f;
        } else {
            xhi[(size_t)n * HIDP + d] = 0;
            xlo[(size_t)n * HIDP + d] = 0;
        }
    }
}

// ---------------- fused edge pipeline via MFMA, 16 edges/block, dst-sorted order ------
// 4 waves split work as (p = j-block parity, half = tile range). 39.4KB LDS -> 4
// blocks/CU -> 16 waves/CU. Edges processed in dst-sorted order (esrc/edst/eorg) so
// the 16 dst rows/block collapse to ~3-4 distinct rows (L1/L2 hits); output scattered
// via eorg. RULE-#20 FIX vs prior rev: all register-ring indices are local-tile-counter
// (tt) based, COMPILE-TIME after unroll; the wave-dependent t0 appears only in address
// arithmetic. (Prior rev indexed rings with t0+tt -> scratch demotion -> 4.5GB spill.)
__global__ __launch_bounds__(256, 4) void edge_fused(
    const ushort* __restrict__ x2hi, const ushort* __restrict__ x2lo,
    const int* __restrict__ esrc, const int* __restrict__ edst,
    const int* __restrict__ eorg, const ushort* __restrict__ T,
    const float* __restrict__ b4, const float* __restrict__ b6,
    const ushort* __restrict__ w8hi, const ushort* __restrict__ w8lo,
    const float* __restrict__ b8, float* __restrict__ out, int E) {
    __shared__ __align__(16) ushort y1h[16 * Y1S];
    __shared__ __align__(16) ushort y1l[16 * Y1S];
    const int tid = threadIdx.x;
    const int wave = tid >> 6, lane = tid & 63;
    const int quad = lane >> 4, l16 = lane & 15;
    const int e0 = blockIdx.x * 16;
    const int p = wave & 1;      // j-block parity this wave owns
    const int half = wave >> 1;  // tile-range half this wave owns
    const int p16 = p * 16;

    int i = e0 + l16;
    if (i >= E) i = E - 1;
    const int s = esrc[i], d = edst[i];
    const ushort* psh = x2hi + (size_t)s * HIDP + quad * 8;  // src row hi
    const ushort* psl = x2lo + (size_t)s * HIDP + quad * 8;  // src row lo
    const ushort* pth = x2hi + (size_t)d * HIDP + quad * 8;  // dst row hi
    const ushort* ptl = x2lo + (size_t)d * HIDP + quad * 8;  // dst row lo

    // chunk m covers ushorts [p16+32m, p16+32m+32); tile (t0+tt) uses chunks
    // t0+tt .. t0+tt+2. Ring slot = LOCAL index (compile-time); chunk t0+m -> slot m&7.
    // chunk 19 is only ever used as c=2 (hi-only) -> skip its lo loads.
    bf8_t Wsh[8], Wsl[8], Wth[8], Wtl[8];
#define LDCH(slot, m)                                     \
    {                                                     \
        const int o_ = p16 + 32 * (m);                    \
        Wsh[slot] = *(const bf8_t*)(psh + o_);            \
        Wth[slot] = *(const bf8_t*)(pth + o_);            \
        if ((m) <= 18) {                                  \
            Wsl[slot] = *(const bf8_t*)(psl + o_);        \
            Wtl[slot] = *(const bf8_t*)(ptl + o_);        \
        }                                                 \
    }
    const int t0 = half * 9;  // conv1 tiles t0..t0+8, chunks t0..t0+10
#pragma unroll
    for (int m = 0; m < 7; m++) LDCH(m, t0 + m);

    // zero tail j in [576, Y1S): conv2 reads up to j=591; never written by conv1.
    for (int idx = tid; idx < 16 * (Y1S - 576); idx += 256) {
        int r = idx / (Y1S - 576);
        int j = 576 + (idx - r * (Y1S - 576));
        y1h[r * Y1S + j] = 0;
        y1l[r * Y1S + j] = 0;
    }

    // Toeplitz conv1 weight frags (loop-invariant). lo frags only needed for c<2.
    bf8_t B1h[2][3], B1l[2][2];
#pragma unroll
    for (int ch = 0; ch < 2; ch++) {
#pragma unroll
        for (int c = 0; c < 3; c++)
            B1h[ch][c] = *(const bf8_t*)&T[(ch * 3 + c) * 512 + lane * 8];
#pragma unroll
        for (int c = 0; c < 2; c++)
            B1l[ch][c] = *(const bf8_t*)&T[((2 + ch) * 3 + c) * 512 + lane * 8];
    }
    const float bb4 = b4[0], bb6 = b6[0];

    // ---- conv1: 9 tiles/wave, 14 MFMA + (early tiles) 4 prefetch loads per tile ----
#pragma unroll
    for (int tt = 0; tt < 9; tt++) {
        if (tt <= 3) LDCH((tt + 7) & 7, t0 + tt + 7);
        const int c0 = tt & 7, c1 = (tt + 1) & 7, c2 = (tt + 2) & 7;  // compile-time
        f4_t acc = {bb4, bb4, bb4, bb4};
        acc = __builtin_amdgcn_mfma_f32_16x16x32_bf16(Wsh[c0], B1h[0][0], acc, 0, 0, 0);
        acc = __builtin_amdgcn_mfma_f32_16x16x32_bf16(Wsl[c0], B1h[0][0], acc, 0, 0, 0);
        acc = __builtin_amdgcn_mfma_f32_16x16x32_bf16(Wsh[c0], B1l[0][0], acc, 0, 0, 0);
        acc = __builtin_amdgcn_mfma_f32_16x16x32_bf16(Wth[c0], B1h[1][0], acc, 0, 0, 0);
        acc = __builtin_amdgcn_mfma_f32_16x16x32_bf16(Wtl[c0], B1h[1][0], acc, 0, 0, 0);
        acc = __builtin_amdgcn_mfma_f32_16x16x32_bf16(Wth[c0], B1l[1][0], acc, 0, 0, 0);
        acc = __builtin_amdgcn_mfma_f32_16x16x32_bf16(Wsh[c1], B1h[0][1], acc, 0, 0, 0);
        acc = __builtin_amdgcn_mfma_f32_16x16x32_bf16(Wsl[c1], B1h[0][1], acc, 0, 0, 0);
        acc = __builtin_amdgcn_mfma_f32_16x16x32_bf16(Wsh[c1], B1l[0][1], acc, 0, 0, 0);
        acc = __builtin_amdgcn_mfma_f32_16x16x32_bf16(Wth[c1], B1h[1][1], acc, 0, 0, 0);
        acc = __builtin_amdgcn_mfma_f32_16x16x32_bf16(Wtl[c1], B1h[1][1], acc, 0, 0, 0);
        acc = __builtin_amdgcn_mfma_f32_16x16x32_bf16(Wth[c1], B1l[1][1], acc, 0, 0, 0);
        acc = __builtin_amdgcn_mfma_f32_16x16x32_bf16(Wsh[c2], B1h[0][2], acc, 0, 0, 0);
        acc = __builtin_amdgcn_mfma_f32_16x16x32_bf16(Wth[c2], B1h[1][2], acc, 0, 0, 0);
        const int j0 = p16 + 32 * (t0 + tt);  // runtime addr arith: fine
#pragma unroll
        for (int r = 0; r < 4; r++) {
            int e_ = quad * 4 + r;
            int pos = e_ * Y1S + j0 + l16;
            float v = acc[r];
            v = v > 0.f ? v : 0.f;
            ushort hh = f2bf_t(v);
            y1h[pos] = hh;
            y1l[pos] = f2bf(v - bf2f(hh));
        }
    }
    __syncthreads();

    // ---- conv2: 8 tiles/wave, sliding LDS chunk ring (2 new ds_reads/tile) ----
    bf8_t B2h[3], B2l[2];
#pragma unroll
    for (int c = 0; c < 3; c++) B2h[c] = *(const bf8_t*)&T[(12 + c) * 512 + lane * 8];
#pragma unroll
    for (int c = 0; c < 2; c++) B2l[c] = *(const bf8_t*)&T[(15 + c) * 512 + lane * 8];
    const int arow1 = l16 * Y1S + quad * 8;
    bf8_t Yh[4], Yl[4];
#define LDY(slot, m)                                          \
    {                                                         \
        const int o_ = arow1 + p16 + 32 * (m);                \
        Yh[slot] = *(const bf8_t*)&y1h[o_];                   \
        if ((m) <= 16) Yl[slot] = *(const bf8_t*)&y1l[o_];    \
    }
    const int t0b = half * 8;  // conv2 tiles t0b..t0b+7, chunks t0b..t0b+9
#pragma unroll
    for (int m = 0; m < 3; m++) LDY(m, t0b + m);
    f4_t zac[8];
#pragma unroll
    for (int tt = 0; tt < 8; tt++) {
        if (tt <= 6) LDY((tt + 3) & 3, t0b + tt + 3);
        const int c0 = tt & 3, c1 = (tt + 1) & 3, c2 = (tt + 2) & 3;  // compile-time
        f4_t acc = {bb6, bb6, bb6, bb6};
        acc = __builtin_amdgcn_mfma_f32_16x16x32_bf16(Yh[c0], B2h[0], acc, 0, 0, 0);
        acc = __builtin_amdgcn_mfma_f32_16x16x32_bf16(Yl[c0], B2h[0], acc, 0, 0, 0);
        acc = __builtin_amdgcn_mfma_f32_16x16x32_bf16(Yh[c0], B2l[0], acc, 0, 0, 0);
        acc = __builtin_amdgcn_mfma_f32_16x16x32_bf16(Yh[c1], B2h[1], acc, 0, 0, 0);
        acc = __builtin_amdgcn_mfma_f32_16x16x32_bf16(Yl[c1], B2h[1], acc, 0, 0, 0);
        acc = __builtin_amdgcn_mfma_f32_16x16x32_bf16(Yh[c1], B2l[1], acc, 0, 0, 0);
        acc = __builtin_amdgcn_mfma_f32_16x16x32_bf16(Yh[c2], B2h[2], acc, 0, 0, 0);
#pragma unroll
        for (int r = 0; r < 4; r++) {
            float v = acc[r];
            zac[tt][r] = v > 0.f ? v : 0.f;
        }
    }
    __syncthreads();  // all conv2 reads of y1 complete before overwrite

    // ---- write z (bf16 hi/lo) into LDS (reusing y1 space), stride ZSS ----
#pragma unroll
    for (int tt = 0; tt < 8; tt++) {
        const int j02 = p16 + 32 * (t0b + tt);
#pragma unroll
        for (int r = 0; r < 4; r++) {
            int e_ = quad * 4 + r;
            int pos = e_ * ZSS + j02 + l16;
            float v = zac[tt][r];
            ushort hh = f2bf_t(v);
            y1h[pos] = hh;
            y1l[pos] = f2bf(v - bf2f(hh));
        }
    }
    __syncthreads();

    // ---- final linear: out = z @ w8^T + b8 (6 col-tiles of 16 over 4 waves) ----
#pragma unroll
    for (int it = 0; it < 2; it++) {
        const int nt = wave + it * 4;
        if (nt < 6) {
            const int col = nt * 16 + l16;
            const int wrow = col < NOUT ? col : 0;
            const float bias = col < NOUT ? b8[col] : 0.f;
            f4_t acc = {bias, bias, bias, bias};
            const int arow = l16 * ZSS + quad * 8;
            const ushort* wph = w8hi + (size_t)wrow * 512 + quad * 8;
            const ushort* wpl = w8lo + (size_t)wrow * 512 + quad * 8;
#pragma unroll
            for (int c = 0; c < 16; c++) {
                bf8_t zh = *(const bf8_t*)&y1h[arow + c * 32];
                bf8_t zl = *(const bf8_t*)&y1l[arow + c * 32];
                bf8_t wh = *(const bf8_t*)(wph + c * 32);
                bf8_t wl = *(const bf8_t*)(wpl + c * 32);
                acc = __builtin_amdgcn_mfma_f32_16x16x32_bf16(zh, wh, acc, 0, 0, 0);
                acc = __builtin_amdgcn_mfma_f32_16x16x32_bf16(zl, wh, acc, 0, 0, 0);
                acc = __builtin_amdgcn_mfma_f32_16x16x32_bf16(zh, wl, acc, 0, 0, 0);
            }
            if (col < NOUT) {
#pragma unroll
                for (int r = 0; r < 4; r++) {
                    int er = e0 + quad * 4 + r;
                    if (er < E) out[(size_t)eorg[er] * NOUT + col] = acc[r];
                }
            }
        }
    }
#undef LDCH
#undef LDY
}

extern "C" void kernel_launch(void* const* d_in, const int* in_sizes, int n_in,
                              void* d_out, int out_size, void* d_ws, size_t ws_size,
                              hipStream_t stream) {
    const float* x = (const float*)d_in[0];
    const int* ei = (const int*)d_in[1];  // int32
    const float* w0 = (const float*)d_in[2];
    const float* b0 = (const float*)d_in[3];
    const float* att_s0 = (const float*)d_in[4];
    const float* att_d0 = (const float*)d_in[5];
    const float* w2 = (const float*)d_in[6];
    const float* b2 = (const float*)d_in[7];
    const float* att_s1 = (const float*)d_in[8];
    const float* att_d1 = (const float*)d_in[9];
    const float* w4 = (const float*)d_in[10];
    const float* b4 = (const float*)d_in[11];
    const float* w6 = (const float*)d_in[12];
    const float* b6 = (const float*)d_in[13];
    const float* w8 = (const float*)d_in[14];
    const float* b8 = (const float*)d_in[15];
    float* out = (float*)d_out;

    const int Nn = in_sizes[0] / FIN;  // 20000
    const int E = in_sizes[1] / 2;     // 100000
    const int HD = HEADS * HID;        // 2440

    // ---- workspace layout (floats); watermark stays under the proven-safe 256.09MB ----
    float* ws = (float*)d_ws;
    size_t o = 0;
    float* buf1 = ws + o; o += (size_t)Nn * HIDP;  // x1/x2 as bf16 hi/lo
    ushort* x1hi = (ushort*)buf1;                  // Nn*HIDP bf16 (hi)
    ushort* x1lo = x1hi + (size_t)Nn * HIDP;       // Nn*HIDP bf16 (lo)
    ushort* w8hi = (ushort*)(ws + o);
    ushort* w8lo = w8hi + (size_t)NOUT * 512; o += (size_t)NOUT * 512;
    int* base = (int*)(ws + o); o += (size_t)Nn + 4;
    int* cursor = (int*)(ws + o); o += (size_t)Nn;  // also hist
    int* esrc = (int*)(ws + o); o += (size_t)E;
    int* edst = (int*)(ws + o); o += (size_t)E;
    int* eorg = (int*)(ws + o); o += (size_t)E;
    float* asrc = ws + o; o += (size_t)Nn * HEADS;
    float* adst = ws + o; o += (size_t)Nn * HEADS;
    ushort* w0hi = (ushort*)(ws + o);
    ushort* w0lo = w0hi + (size_t)HD * FIN; o += (size_t)HD * FIN;
    ushort* w2hi = (ushort*)(ws + o);
    ushort* w2lo = w2hi + (size_t)HD * HIDP; o += (size_t)HD * HIDP;
    float* h = ws + o;  // Nn*2440 fp32

    int edgeGrid = (E + 255) / 256;
    int nodeWaveGrid = (Nn + 3) / 4;
    int fusedGrid = (E + 15) / 16;
    dim3 gGemmL((HD + 127) / 128, (Nn + 127) / 128);   // 20 x 157

    // ---- one-time: weight split + edge sort by dst ----
    split_pad<<<((HD * FIN) + 255) / 256, 256, 0, stream>>>(w0, w0hi, w0lo, HD, FIN, FIN);
    split_pad<<<((HD * HIDP) + 255) / 256, 256, 0, stream>>>(w2, w2hi, w2lo, HD, HID, HIDP);
    split_pad<<<((NOUT * 512) + 255) / 256, 256, 0, stream>>>(w8, w8hi, w8lo, NOUT, 512, 512);
    fill_val<<<(Nn + 255) / 256, 256, 0, stream>>>((float*)cursor, 0.f, Nn);  // hist=0
    hist_k<<<edgeGrid, 256, 0, stream>>>(ei, cursor, E);
    scan_k<<<1, 1024, 0, stream>>>(cursor, base, Nn);
    copy_int<<<(Nn + 255) / 256, 256, 0, stream>>>(base, cursor, Nn);
    scatter_k<<<edgeGrid, 256, 0, stream>>>(ei, cursor, esrc, edst, eorg, E);

    // ---------- GAT layer 1 ----------
    gemm_mfma<0, false><<<gGemmL, 256, 0, stream>>>(x, nullptr, nullptr, w0hi, w0lo, nullptr,
                                                    h, Nn, HD, FIN);
    // w0hi slot is dead after gemm L1 -> reuse it for the Toeplitz frag table (18*512 ushorts)
    build_toeplitz<<<(18 * 512 + 255) / 256, 256, 0, stream>>>(w4, w6, w0hi);
    attn_dots<<<Nn, 256, 0, stream>>>(h, att_s0, att_d0, asrc, adst, Nn);
    node_aggregate<1><<<nodeWaveGrid, 256, 0, stream>>>(h, asrc, adst, base, esrc, b0,
                                                        nullptr, x1hi, x1lo, Nn);

    // ---------- GAT layer 2 (A pre-split: no conversion VALU in hot loop) ----------
    gemm_mfma<1, false><<<gGemmL, 256, 0, stream>>>(nullptr, x1hi, x1lo, w2hi, w2lo, nullptr,
                                                    h, Nn, HD, HIDP);
    attn_dots<<<Nn, 256, 0, stream>>>(h, att_s1, att_d1, asrc, adst, Nn);
    // layer-2 output written directly as bf16 hi/lo (consumed by MFMA conv)
    node_aggregate<1><<<nodeWaveGrid, 256, 0, stream>>>(h, asrc, adst, base, esrc, b2,
                                                        nullptr, x1hi, x1lo, Nn);

    // ---------- fused edge conv1+conv2+final linear (MFMA, 16 edges/block, dst-sorted) ----
    edge_fused<<<fusedGrid, 256, 0, stream>>>(x1hi, x1lo, esrc, edst, eorg, w0hi, b4, b6,
                                              w8hi, w8lo, b8, out, E);
}

// Round 5
// 1053.515 us; speedup vs baseline: 2.6340x; 1.1478x over previous
//
#include <hip/hip_runtime.h>
#include <math.h>

#define HEADS 4
#define HID 610
#define HIDP 640   // K-padded row stride for MFMA (mult of 32)
#define FIN 128
#define KER 50
#define NOUT 86
#define NEG_SLOPE 0.2f

#define Y1S 616    // y1 LDS row stride (ushorts): 308 words, %32=20 -> 2-way banks, no swizzle
#define ZSS 520    // z LDS row stride (ushorts): 260 words, %32=4 -> 2-way banks

typedef short bf8_t __attribute__((ext_vector_type(8)));  // 8 bf16 (4 VGPRs)
typedef float f4_t __attribute__((ext_vector_type(4)));   // MFMA C/D

__device__ __forceinline__ ushort f2bf(float f) {  // RNE fp32->bf16
    unsigned u = __float_as_uint(f);
    unsigned r = (u + 0x7FFFu + ((u >> 16) & 1u)) >> 16;
    return (ushort)r;
}
__device__ __forceinline__ ushort f2bf_t(float f) {  // truncating split-hi (residual goes to lo)
    return (ushort)(__float_as_uint(f) >> 16);
}
__device__ __forceinline__ float bf2f(ushort b) { return __uint_as_float(((unsigned)b) << 16); }

// ---------------- utility ----------------
__global__ void fill_val(float* __restrict__ p, float v, long n) {
    long i = (long)blockIdx.x * blockDim.x + threadIdx.x;
    if (i < n) p[i] = v;
}

__global__ void copy_int(const int* __restrict__ a, int* __restrict__ b, int n) {
    int i = blockIdx.x * blockDim.x + threadIdx.x;
    if (i < n) b[i] = a[i];
}

// ---------------- edge sort by dst: histogram / scan / scatter ----------------
__global__ void hist_k(const int* __restrict__ ei, int* __restrict__ hist, int E) {
    int e = blockIdx.x * blockDim.x + threadIdx.x;
    if (e < E) atomicAdd(&hist[ei[E + e]], 1);
}

__global__ __launch_bounds__(1024) void scan_k(const int* __restrict__ hist,
                                               int* __restrict__ base, int Nn) {
    __shared__ int tmp[1024];
    __shared__ int carry;
    if (threadIdx.x == 0) carry = 0;
    __syncthreads();
    for (int c0 = 0; c0 < Nn; c0 += 1024) {
        int i = c0 + threadIdx.x;
        int v = (i < Nn) ? hist[i] : 0;
        tmp[threadIdx.x] = v;
        __syncthreads();
        for (int off = 1; off < 1024; off <<= 1) {
            int t = (threadIdx.x >= off) ? tmp[threadIdx.x - off] : 0;
            __syncthreads();
            tmp[threadIdx.x] += t;
            __syncthreads();
        }
        if (i < Nn) base[i] = carry + tmp[threadIdx.x] - v;  // exclusive
        __syncthreads();
        if (threadIdx.x == 1023) carry += tmp[1023];
        __syncthreads();
    }
    if (threadIdx.x == 0) base[Nn] = carry;
}

// scatter also records dst node and original edge id per sorted slot, so the fused
// edge kernel can process edges in dst-sorted order (dst-row gathers become L1/L2 hits)
__global__ void scatter_k(const int* __restrict__ ei, int* __restrict__ cursor,
                          int* __restrict__ esrc, int* __restrict__ edst,
                          int* __restrict__ eorg, int E) {
    int e = blockIdx.x * blockDim.x + threadIdx.x;
    if (e >= E) return;
    int d = ei[E + e];
    int pos = atomicAdd(&cursor[d], 1);
    esrc[pos] = ei[e];
    edst[pos] = d;
    eorg[pos] = e;
}

// ---------------- split fp32 -> bf16 hi/lo with K padding ----------------
__global__ void split_pad(const float* __restrict__ in, ushort* __restrict__ hi,
                          ushort* __restrict__ lo, int R, int K, int Kp) {
    long i = (long)blockIdx.x * blockDim.x + threadIdx.x;
    if (i >= (long)R * Kp) return;
    int r = (int)(i / Kp), c = (int)(i % Kp);
    float v = (c < K) ? in[(long)r * K + c] : 0.f;
    ushort h = f2bf(v);
    hi[i] = h;
    lo[i] = f2bf(v - bf2f(h));
}

// ---------------- Toeplitz weight-fragment tables for conv-as-MFMA ----------------
// 18 fragments of 512 ushorts each (frag f at T[f*512 + lane*8 + e]):
//   f = (hilo*2 + ch)*3 + c   (f<12): conv1, B[n,kk]=w4[ch*KER + (32c + k - n)]
//   f = 12 + hilo*3 + c       (f<18): conv2, B[n,kk]=w6[32c + k - n]
// with n = lane&15, k = (lane>>4)*8 + e  (16x16x32 B-fragment layout).
__global__ void build_toeplitz(const float* __restrict__ w4, const float* __restrict__ w6,
                               ushort* __restrict__ T) {
    int i = blockIdx.x * blockDim.x + threadIdx.x;
    if (i >= 18 * 512) return;
    int e = i & 7;
    int lane = (i >> 3) & 63;
    int f = i >> 9;
    int n = lane & 15;
    int k = ((lane >> 4) << 3) + e;
    float wv;
    int hilo;
    if (f < 12) {
        int c = f % 3, hc = f / 3;
        int ch = hc & 1;
        hilo = hc >> 1;
        int d = c * 32 + k - n;
        wv = (d >= 0 && d < KER) ? w4[ch * KER + d] : 0.f;
    } else {
        int r2 = f - 12;
        int c = r2 % 3;
        hilo = r2 / 3;
        int d = c * 32 + k - n;
        wv = (d >= 0 && d < KER) ? w6[d] : 0.f;
    }
    ushort h = f2bf(wv);
    T[i] = hilo ? f2bf(wv - bf2f(h)) : h;
}

// ---------------- split-bf16 MFMA GEMM: C[M,N] = A[M,Kp] * B[N,Kp]^T (+bias) ----------------
template <int AMODE, bool BIAS>
__global__ __launch_bounds__(256) void gemm_mfma(const float* __restrict__ A,
                                                 const ushort* __restrict__ Aghi,
                                                 const ushort* __restrict__ Aglo,
                                                 const ushort* __restrict__ Bghi,
                                                 const ushort* __restrict__ Bglo,
                                                 const float* __restrict__ bias,
                                                 float* __restrict__ C,
                                                 int M, int N, int Kp) {
    __shared__ __align__(16) ushort Ah[128 * 32];
    __shared__ __align__(16) ushort Al[128 * 32];
    __shared__ __align__(16) ushort Bh[128 * 32];
    __shared__ __align__(16) ushort Bl[128 * 32];
    int tid = threadIdx.x;
    int wave = tid >> 6, lane = tid & 63;
    int quad = lane >> 4, l16 = lane & 15;
    int wm = wave & 1, wn = wave >> 1;
    int row0 = blockIdx.y * 128, col0 = blockIdx.x * 128;

    float4 pa0[4];
    uint4 pah[2], pal[2], pbh[2], pbl[2];

    auto loadA = [&](int k0) {
        if (AMODE == 0) {
#pragma unroll
            for (int q = 0; q < 4; q++) {
                int p = tid + q * 256;
                int r = p >> 3, c4 = (p & 7) << 2;
                int gr = row0 + r;
                pa0[q] = (gr < M) ? *(const float4*)(A + (size_t)gr * Kp + k0 + c4)
                                  : make_float4(0.f, 0.f, 0.f, 0.f);
            }
        } else {
#pragma unroll
            for (int q = 0; q < 2; q++) {
                int p = tid + q * 256;
                int r = p >> 2, c = p & 3;
                int gr = row0 + r;
                if (gr < M) {
                    pah[q] = *(const uint4*)(Aghi + (size_t)gr * Kp + k0 + c * 8);
                    pal[q] = *(const uint4*)(Aglo + (size_t)gr * Kp + k0 + c * 8);
                } else {
                    pah[q] = make_uint4(0, 0, 0, 0);
                    pal[q] = make_uint4(0, 0, 0, 0);
                }
            }
        }
    };
    auto loadB = [&](int k0) {
#pragma unroll
        for (int q = 0; q < 2; q++) {
            int p = tid + q * 256;
            int r = p >> 2, c = p & 3;
            int gr = col0 + r;
            if (gr < N) {
                pbh[q] = *(const uint4*)(Bghi + (size_t)gr * Kp + k0 + c * 8);
                pbl[q] = *(const uint4*)(Bglo + (size_t)gr * Kp + k0 + c * 8);
            } else {
                pbh[q] = make_uint4(0, 0, 0, 0);
                pbl[q] = make_uint4(0, 0, 0, 0);
            }
        }
    };
    auto writeLDS = [&]() {
        if (AMODE == 0) {
#pragma unroll
            for (int q = 0; q < 4; q++) {
                int p = tid + q * 256;
                int r = p >> 3, m = p & 7;
                int pos = r * 32 + ((((m >> 1)) ^ ((r >> 1) & 3)) << 3) + ((m & 1) << 2);
                float4 v = pa0[q];
                ushort4 hv, lv;
                hv.x = f2bf(v.x); lv.x = f2bf(v.x - bf2f(hv.x));
                hv.y = f2bf(v.y); lv.y = f2bf(v.y - bf2f(hv.y));
                hv.z = f2bf(v.z); lv.z = f2bf(v.z - bf2f(hv.z));
                hv.w = f2bf(v.w); lv.w = f2bf(v.w - bf2f(hv.w));
                *(ushort4*)&Ah[pos] = hv;
                *(ushort4*)&Al[pos] = lv;
            }
        } else {
#pragma unroll
            for (int q = 0; q < 2; q++) {
                int p = tid + q * 256;
                int r = p >> 2, c = p & 3;
                int pos = r * 32 + ((c ^ ((r >> 1) & 3)) << 3);
                *(uint4*)&Ah[pos] = pah[q];
                *(uint4*)&Al[pos] = pal[q];
            }
        }
#pragma unroll
        for (int q = 0; q < 2; q++) {
            int p = tid + q * 256;
            int r = p >> 2, c = p & 3;
            int pos = r * 32 + ((c ^ ((r >> 1) & 3)) << 3);
            *(uint4*)&Bh[pos] = pbh[q];
            *(uint4*)&Bl[pos] = pbl[q];
        }
    };

    f4_t acc[4][4];
#pragma unroll
    for (int i = 0; i < 4; i++)
#pragma unroll
        for (int j = 0; j < 4; j++) acc[i][j] = (f4_t){0.f, 0.f, 0.f, 0.f};

    loadA(0);
    loadB(0);
    int sw = (quad ^ ((l16 >> 1) & 3)) << 3;
    for (int k0 = 0; k0 < Kp; k0 += 32) {
        __syncthreads();
        writeLDS();
        __syncthreads();
        if (k0 + 32 < Kp) {
            loadA(k0 + 32);
            loadB(k0 + 32);
        }
        bf8_t ah[4], al[4], bh[4], bl[4];
#pragma unroll
        for (int t = 0; t < 4; t++) {
            int ar = wm * 64 + t * 16 + l16;
            ah[t] = *(const bf8_t*)&Ah[ar * 32 + sw];
            al[t] = *(const bf8_t*)&Al[ar * 32 + sw];
            int br = wn * 64 + t * 16 + l16;
            bh[t] = *(const bf8_t*)&Bh[br * 32 + sw];
            bl[t] = *(const bf8_t*)&Bl[br * 32 + sw];
        }
#pragma unroll
        for (int i = 0; i < 4; i++)
#pragma unroll
            for (int j = 0; j < 4; j++) {
                acc[i][j] = __builtin_amdgcn_mfma_f32_16x16x32_bf16(ah[i], bh[j], acc[i][j], 0, 0, 0);
                acc[i][j] = __builtin_amdgcn_mfma_f32_16x16x32_bf16(al[i], bh[j], acc[i][j], 0, 0, 0);
                acc[i][j] = __builtin_amdgcn_mfma_f32_16x16x32_bf16(ah[i], bl[j], acc[i][j], 0, 0, 0);
            }
    }
    // epilogue: D row(m)=quad*4+reg, col(n)=lane&15
#pragma unroll
    for (int i = 0; i < 4; i++) {
#pragma unroll
        for (int r = 0; r < 4; r++) {
            int grow = row0 + wm * 64 + i * 16 + quad * 4 + r;
            if (grow >= M) continue;
#pragma unroll
            for (int j = 0; j < 4; j++) {
                int gcol = col0 + wn * 64 + j * 16 + l16;
                if (gcol >= N) continue;
                float v = acc[i][j][r];
                if (BIAS) v += bias[gcol];
                C[(size_t)grow * N + gcol] = v;
            }
        }
    }
}

// ---------------- attention dot products per node/head ----------------
__global__ __launch_bounds__(256) void attn_dots(const float* __restrict__ h,
                                                 const float* __restrict__ att_s,
                                                 const float* __restrict__ att_d,
                                                 float* __restrict__ a_src,
                                                 float* __restrict__ a_dst, int Nn) {
    int n = blockIdx.x;
    int head = threadIdx.x >> 6;
    int lane = threadIdx.x & 63;
    const float2* hr = (const float2*)(h + (long)n * (HEADS * HID) + head * HID);
    const float2* as = (const float2*)(att_s + head * HID);
    const float2* ad = (const float2*)(att_d + head * HID);
    float ss = 0.f, sd = 0.f;
    for (int d = lane; d < HID / 2; d += 64) {
        float2 hv = hr[d], av = as[d], dv = ad[d];
        ss += hv.x * av.x + hv.y * av.y;
        sd += hv.x * dv.x + hv.y * dv.y;
    }
    for (int off = 32; off > 0; off >>= 1) {
        ss += __shfl_down(ss, off);
        sd += __shfl_down(sd, off);
    }
    if (lane == 0) {
        a_src[n * HEADS + head] = ss;
        a_dst[n * HEADS + head] = sd;
    }
}

// ---------------- per-dst-node softmax + aggregation (atomic-free, CSR) ----------------
template <int OUTMODE>
__global__ __launch_bounds__(256) void node_aggregate(
    const float* __restrict__ h, const float* __restrict__ asrc,
    const float* __restrict__ adst, const int* __restrict__ base,
    const int* __restrict__ esrc, const float* __restrict__ bias,
    float* __restrict__ xout, ushort* __restrict__ xhi, ushort* __restrict__ xlo,
    int Nn) {
    int wave = threadIdx.x >> 6, lane = threadIdx.x & 63;
    int n = blockIdx.x * 4 + wave;
    if (n >= Nn) return;
    int b0 = base[n], deg = base[n + 1] - b0;
    float ad[HEADS];
#pragma unroll
    for (int hh = 0; hh < HEADS; hh++) ad[hh] = adst[n * HEADS + hh];
    float m[HEADS] = {-INFINITY, -INFINITY, -INFINITY, -INFINITY};
    for (int eb = 0; eb < deg; eb += 64) {
        int i = eb + lane;
        if (i < deg) {
            int s = esrc[b0 + i];
#pragma unroll
            for (int hh = 0; hh < HEADS; hh++) {
                float v = asrc[s * HEADS + hh] + ad[hh];
                v = v >= 0.f ? v : NEG_SLOPE * v;
                m[hh] = fmaxf(m[hh], v);
            }
        }
    }
#pragma unroll
    for (int off = 32; off > 0; off >>= 1)
#pragma unroll
        for (int hh = 0; hh < HEADS; hh++) m[hh] = fmaxf(m[hh], __shfl_xor(m[hh], off));
    float sden[HEADS] = {0.f, 0.f, 0.f, 0.f};
    for (int eb = 0; eb < deg; eb += 64) {
        int i = eb + lane;
        if (i < deg) {
            int s = esrc[b0 + i];
#pragma unroll
            for (int hh = 0; hh < HEADS; hh++) {
                float v = asrc[s * HEADS + hh] + ad[hh];
                v = v >= 0.f ? v : NEG_SLOPE * v;
                sden[hh] += expf(v - m[hh]);
            }
        }
    }
#pragma unroll
    for (int off = 32; off > 0; off >>= 1)
#pragma unroll
        for (int hh = 0; hh < HEADS; hh++) sden[hh] += __shfl_xor(sden[hh], off);
    float inv[HEADS];
#pragma unroll
    for (int hh = 0; hh < HEADS; hh++) inv[hh] = 0.25f / (sden[hh] + 1e-16f);
    float acc0[10] = {}, acc1[10] = {}, acc2[10] = {}, acc3[10] = {};
    for (int eb = 0; eb < deg; eb += 64) {
        int i = eb + lane;
        int sreg = 0;
        float coef[HEADS] = {0.f, 0.f, 0.f, 0.f};
        if (i < deg) {
            sreg = esrc[b0 + i];
#pragma unroll
            for (int hh = 0; hh < HEADS; hh++) {
                float v = asrc[sreg * HEADS + hh] + ad[hh];
                v = v >= 0.f ? v : NEG_SLOPE * v;
                coef[hh] = expf(v - m[hh]) * inv[hh];
            }
        }
        int cnt = deg - eb < 64 ? deg - eb : 64;
        for (int j = 0; j < cnt; j++) {
            int s = __shfl(sreg, j);
            float c0 = __shfl(coef[0], j), c1 = __shfl(coef[1], j);
            float c2 = __shfl(coef[2], j), c3 = __shfl(coef[3], j);
            const float* hr = h + (size_t)s * (HEADS * HID);
#pragma unroll
            for (int t = 0; t < 10; t++) {
                int d = lane + t * 64;
                if (d < HID) {
                    acc0[t] = fmaf(c0, hr[d], acc0[t]);
                    acc1[t] = fmaf(c1, hr[HID + d], acc1[t]);
                    acc2[t] = fmaf(c2, hr[2 * HID + d], acc2[t]);
                    acc3[t] = fmaf(c3, hr[3 * HID + d], acc3[t]);
                }
            }
        }
    }
#pragma unroll
    for (int t = 0; t < 10; t++) {
        int d = lane + t * 64;
        if (d < HID) {
            float v = acc0[t] + acc1[t] + acc2[t] + acc3[t] + bias[d];
            v = v > 0.f ? v : 0.f;
            if (OUTMODE == 0) {
                xout[(size_t)n * HIDP + d] = v;
            } else {
                ushort hv = f2bf(v);
                xhi[(size_t)n * HIDP + d] = hv;
                xlo[(size_t)n * HIDP + d] = f2bf(v - bf2f(hv));
            }
        }
    }
    for (int d = HID + lane; d < HIDP; d += 64) {
        if (OUTMODE == 0) {
            xout[(size_t)n * HIDP + d] = 0.f;
        } else {
            xhi[(size_t)n * HIDP + d] = 0;
            xlo[(size_t)n * HIDP + d] = 0;
        }
    }
}

// ---------------- fused edge pipeline via MFMA, 16 edges/block, dst-sorted order ------
// 4 waves split work as (p = j-block parity, half = tile range). 39.4KB LDS + VGPR cap
// ~170 (launch_bounds(256,3)) -> 3 blocks/CU = 12 waves/CU, NO SPILLS (prior rev's
// (256,4) cap of 128 VGPR forced ~600MB of scratch traffic -> HBM-bound on spills).
// conv1 ring is 6-deep (96 VGPR) with 3-tile lookahead; all ring indices are local
// compile-time constants (rule #20). Edges processed in dst-sorted order (esrc/edst/
// eorg) so dst-row gathers hit L1/L2; output scattered via eorg.
__global__ __launch_bounds__(256, 3) void edge_fused(
    const ushort* __restrict__ x2hi, const ushort* __restrict__ x2lo,
    const int* __restrict__ esrc, const int* __restrict__ edst,
    const int* __restrict__ eorg, const ushort* __restrict__ T,
    const float* __restrict__ b4, const float* __restrict__ b6,
    const ushort* __restrict__ w8hi, const ushort* __restrict__ w8lo,
    const float* __restrict__ b8, float* __restrict__ out, int E) {
    __shared__ __align__(16) ushort y1h[16 * Y1S];
    __shared__ __align__(16) ushort y1l[16 * Y1S];
    const int tid = threadIdx.x;
    const int wave = tid >> 6, lane = tid & 63;
    const int quad = lane >> 4, l16 = lane & 15;
    const int e0 = blockIdx.x * 16;
    const int p = wave & 1;      // j-block parity this wave owns
    const int half = wave >> 1;  // tile-range half this wave owns
    const int p16 = p * 16;

    int i = e0 + l16;
    if (i >= E) i = E - 1;
    const int s = esrc[i], d = edst[i];
    const ushort* psh = x2hi + (size_t)s * HIDP + quad * 8;  // src row hi
    const ushort* psl = x2lo + (size_t)s * HIDP + quad * 8;  // src row lo
    const ushort* pth = x2hi + (size_t)d * HIDP + quad * 8;  // dst row hi
    const ushort* ptl = x2lo + (size_t)d * HIDP + quad * 8;  // dst row lo

    // chunk m (global) covers ushorts [p16+32m, p16+32m+32); tile (t0+tt) uses chunks
    // t0+tt..t0+tt+2. Ring slot = LOCAL index % 6 (compile-time after unroll).
    // Global chunk 19 is only ever used as c=2 (hi-only) -> skip its lo loads.
    bf8_t Wsh[6], Wsl[6], Wth[6], Wtl[6];
#define LDCH(slot, m)                                     \
    {                                                     \
        const int o_ = p16 + 32 * (m);                    \
        Wsh[slot] = *(const bf8_t*)(psh + o_);            \
        Wth[slot] = *(const bf8_t*)(pth + o_);            \
        if ((m) <= 18) {                                  \
            Wsl[slot] = *(const bf8_t*)(psl + o_);        \
            Wtl[slot] = *(const bf8_t*)(ptl + o_);        \
        }                                                 \
    }
    const int t0 = half * 9;  // conv1 tiles t0..t0+8, chunks t0..t0+10
#pragma unroll
    for (int m = 0; m < 5; m++) LDCH(m, t0 + m);

    // zero tail j in [576, Y1S): conv2 reads up to j=591; never written by conv1.
    for (int idx = tid; idx < 16 * (Y1S - 576); idx += 256) {
        int r = idx / (Y1S - 576);
        int j = 576 + (idx - r * (Y1S - 576));
        y1h[r * Y1S + j] = 0;
        y1l[r * Y1S + j] = 0;
    }

    // Toeplitz conv1 weight frags (loop-invariant). lo frags only needed for c<2.
    bf8_t B1h[2][3], B1l[2][2];
#pragma unroll
    for (int ch = 0; ch < 2; ch++) {
#pragma unroll
        for (int c = 0; c < 3; c++)
            B1h[ch][c] = *(const bf8_t*)&T[(ch * 3 + c) * 512 + lane * 8];
#pragma unroll
        for (int c = 0; c < 2; c++)
            B1l[ch][c] = *(const bf8_t*)&T[((2 + ch) * 3 + c) * 512 + lane * 8];
    }
    const float bb4 = b4[0], bb6 = b6[0];

    // ---- conv1: 9 tiles/wave, 14 MFMA/tile, 6-deep ring, 3-tile lookahead ----
#pragma unroll
    for (int tt = 0; tt < 9; tt++) {
        if (tt <= 5) LDCH((tt + 5) % 6, t0 + tt + 5);
        const int c0 = tt % 6, c1 = (tt + 1) % 6, c2 = (tt + 2) % 6;  // compile-time
        f4_t acc = {bb4, bb4, bb4, bb4};
        acc = __builtin_amdgcn_mfma_f32_16x16x32_bf16(Wsh[c0], B1h[0][0], acc, 0, 0, 0);
        acc = __builtin_amdgcn_mfma_f32_16x16x32_bf16(Wsl[c0], B1h[0][0], acc, 0, 0, 0);
        acc = __builtin_amdgcn_mfma_f32_16x16x32_bf16(Wsh[c0], B1l[0][0], acc, 0, 0, 0);
        acc = __builtin_amdgcn_mfma_f32_16x16x32_bf16(Wth[c0], B1h[1][0], acc, 0, 0, 0);
        acc = __builtin_amdgcn_mfma_f32_16x16x32_bf16(Wtl[c0], B1h[1][0], acc, 0, 0, 0);
        acc = __builtin_amdgcn_mfma_f32_16x16x32_bf16(Wth[c0], B1l[1][0], acc, 0, 0, 0);
        acc = __builtin_amdgcn_mfma_f32_16x16x32_bf16(Wsh[c1], B1h[0][1], acc, 0, 0, 0);
        acc = __builtin_amdgcn_mfma_f32_16x16x32_bf16(Wsl[c1], B1h[0][1], acc, 0, 0, 0);
        acc = __builtin_amdgcn_mfma_f32_16x16x32_bf16(Wsh[c1], B1l[0][1], acc, 0, 0, 0);
        acc = __builtin_amdgcn_mfma_f32_16x16x32_bf16(Wth[c1], B1h[1][1], acc, 0, 0, 0);
        acc = __builtin_amdgcn_mfma_f32_16x16x32_bf16(Wtl[c1], B1h[1][1], acc, 0, 0, 0);
        acc = __builtin_amdgcn_mfma_f32_16x16x32_bf16(Wth[c1], B1l[1][1], acc, 0, 0, 0);
        acc = __builtin_amdgcn_mfma_f32_16x16x32_bf16(Wsh[c2], B1h[0][2], acc, 0, 0, 0);
        acc = __builtin_amdgcn_mfma_f32_16x16x32_bf16(Wth[c2], B1h[1][2], acc, 0, 0, 0);
        const int j0 = p16 + 32 * (t0 + tt);  // runtime addr arith: fine
#pragma unroll
        for (int r = 0; r < 4; r++) {
            int e_ = quad * 4 + r;
            int pos = e_ * Y1S + j0 + l16;
            float v = acc[r];
            v = v > 0.f ? v : 0.f;
            ushort hh = f2bf_t(v);
            y1h[pos] = hh;
            y1l[pos] = f2bf(v - bf2f(hh));
        }
    }
    __syncthreads();

    // ---- conv2: 8 tiles/wave, sliding LDS chunk ring (2 new ds_reads/tile) ----
    bf8_t B2h[3], B2l[2];
#pragma unroll
    for (int c = 0; c < 3; c++) B2h[c] = *(const bf8_t*)&T[(12 + c) * 512 + lane * 8];
#pragma unroll
    for (int c = 0; c < 2; c++) B2l[c] = *(const bf8_t*)&T[(15 + c) * 512 + lane * 8];
    const int arow1 = l16 * Y1S + quad * 8;
    bf8_t Yh[4], Yl[4];
#define LDY(slot, m)                                          \
    {                                                         \
        const int o_ = arow1 + p16 + 32 * (m);                \
        Yh[slot] = *(const bf8_t*)&y1h[o_];                   \
        if ((m) <= 16) Yl[slot] = *(const bf8_t*)&y1l[o_];    \
    }
    const int t0b = half * 8;  // conv2 tiles t0b..t0b+7, chunks t0b..t0b+9
#pragma unroll
    for (int m = 0; m < 3; m++) LDY(m, t0b + m);
    f4_t zac[8];
#pragma unroll
    for (int tt = 0; tt < 8; tt++) {
        if (tt <= 6) LDY((tt + 3) & 3, t0b + tt + 3);
        const int c0 = tt & 3, c1 = (tt + 1) & 3, c2 = (tt + 2) & 3;  // compile-time
        f4_t acc = {bb6, bb6, bb6, bb6};
        acc = __builtin_amdgcn_mfma_f32_16x16x32_bf16(Yh[c0], B2h[0], acc, 0, 0, 0);
        acc = __builtin_amdgcn_mfma_f32_16x16x32_bf16(Yl[c0], B2h[0], acc, 0, 0, 0);
        acc = __builtin_amdgcn_mfma_f32_16x16x32_bf16(Yh[c0], B2l[0], acc, 0, 0, 0);
        acc = __builtin_amdgcn_mfma_f32_16x16x32_bf16(Yh[c1], B2h[1], acc, 0, 0, 0);
        acc = __builtin_amdgcn_mfma_f32_16x16x32_bf16(Yl[c1], B2h[1], acc, 0, 0, 0);
        acc = __builtin_amdgcn_mfma_f32_16x16x32_bf16(Yh[c1], B2l[1], acc, 0, 0, 0);
        acc = __builtin_amdgcn_mfma_f32_16x16x32_bf16(Yh[c2], B2h[2], acc, 0, 0, 0);
#pragma unroll
        for (int r = 0; r < 4; r++) {
            float v = acc[r];
            zac[tt][r] = v > 0.f ? v : 0.f;
        }
    }
    __syncthreads();  // all conv2 reads of y1 complete before overwrite

    // ---- write z (bf16 hi/lo) into LDS (reusing y1 space), stride ZSS ----
#pragma unroll
    for (int tt = 0; tt < 8; tt++) {
        const int j02 = p16 + 32 * (t0b + tt);
#pragma unroll
        for (int r = 0; r < 4; r++) {
            int e_ = quad * 4 + r;
            int pos = e_ * ZSS + j02 + l16;
            float v = zac[tt][r];
            ushort hh = f2bf_t(v);
            y1h[pos] = hh;
            y1l[pos] = f2bf(v - bf2f(hh));
        }
    }
    __syncthreads();

    // ---- final linear: out = z @ w8^T + b8 (6 col-tiles of 16 over 4 waves) ----
#pragma unroll
    for (int it = 0; it < 2; it++) {
        const int nt = wave + it * 4;
        if (nt < 6) {
            const int col = nt * 16 + l16;
            const int wrow = col < NOUT ? col : 0;
            const float bias = col < NOUT ? b8[col] : 0.f;
            f4_t acc = {bias, bias, bias, bias};
            const int arow = l16 * ZSS + quad * 8;
            const ushort* wph = w8hi + (size_t)wrow * 512 + quad * 8;
            const ushort* wpl = w8lo + (size_t)wrow * 512 + quad * 8;
#pragma unroll
            for (int c = 0; c < 16; c++) {
                bf8_t zh = *(const bf8_t*)&y1h[arow + c * 32];
                bf8_t zl = *(const bf8_t*)&y1l[arow + c * 32];
                bf8_t wh = *(const bf8_t*)(wph + c * 32);
                bf8_t wl = *(const bf8_t*)(wpl + c * 32);
                acc = __builtin_amdgcn_mfma_f32_16x16x32_bf16(zh, wh, acc, 0, 0, 0);
                acc = __builtin_amdgcn_mfma_f32_16x16x32_bf16(zl, wh, acc, 0, 0, 0);
                acc = __builtin_amdgcn_mfma_f32_16x16x32_bf16(zh, wl, acc, 0, 0, 0);
            }
            if (col < NOUT) {
#pragma unroll
                for (int r = 0; r < 4; r++) {
                    int er = e0 + quad * 4 + r;
                    if (er < E) out[(size_t)eorg[er] * NOUT + col] = acc[r];
                }
            }
        }
    }
#undef LDCH
#undef LDY
}

extern "C" void kernel_launch(void* const* d_in, const int* in_sizes, int n_in,
                              void* d_out, int out_size, void* d_ws, size_t ws_size,
                              hipStream_t stream) {
    const float* x = (const float*)d_in[0];
    const int* ei = (const int*)d_in[1];  // int32
    const float* w0 = (const float*)d_in[2];
    const float* b0 = (const float*)d_in[3];
    const float* att_s0 = (const float*)d_in[4];
    const float* att_d0 = (const float*)d_in[5];
    const float* w2 = (const float*)d_in[6];
    const float* b2 = (const float*)d_in[7];
    const float* att_s1 = (const float*)d_in[8];
    const float* att_d1 = (const float*)d_in[9];
    const float* w4 = (const float*)d_in[10];
    const float* b4 = (const float*)d_in[11];
    const float* w6 = (const float*)d_in[12];
    const float* b6 = (const float*)d_in[13];
    const float* w8 = (const float*)d_in[14];
    const float* b8 = (const float*)d_in[15];
    float* out = (float*)d_out;

    const int Nn = in_sizes[0] / FIN;  // 20000
    const int E = in_sizes[1] / 2;     // 100000
    const int HD = HEADS * HID;        // 2440

    // ---- workspace layout (floats); watermark stays under the proven-safe 256.09MB ----
    float* ws = (float*)d_ws;
    size_t o = 0;
    float* buf1 = ws + o; o += (size_t)Nn * HIDP;  // x1/x2 as bf16 hi/lo
    ushort* x1hi = (ushort*)buf1;                  // Nn*HIDP bf16 (hi)
    ushort* x1lo = x1hi + (size_t)Nn * HIDP;       // Nn*HIDP bf16 (lo)
    ushort* w8hi = (ushort*)(ws + o);
    ushort* w8lo = w8hi + (size_t)NOUT * 512; o += (size_t)NOUT * 512;
    int* base = (int*)(ws + o); o += (size_t)Nn + 4;
    int* cursor = (int*)(ws + o); o += (size_t)Nn;  // also hist
    int* esrc = (int*)(ws + o); o += (size_t)E;
    int* edst = (int*)(ws + o); o += (size_t)E;
    int* eorg = (int*)(ws + o); o += (size_t)E;
    float* asrc = ws + o; o += (size_t)Nn * HEADS;
    float* adst = ws + o; o += (size_t)Nn * HEADS;
    ushort* w0hi = (ushort*)(ws + o);
    ushort* w0lo = w0hi + (size_t)HD * FIN; o += (size_t)HD * FIN;
    ushort* w2hi = (ushort*)(ws + o);
    ushort* w2lo = w2hi + (size_t)HD * HIDP; o += (size_t)HD * HIDP;
    float* h = ws + o;  // Nn*2440 fp32

    int edgeGrid = (E + 255) / 256;
    int nodeWaveGrid = (Nn + 3) / 4;
    int fusedGrid = (E + 15) / 16;
    dim3 gGemmL((HD + 127) / 128, (Nn + 127) / 128);   // 20 x 157

    // ---- one-time: weight split + edge sort by dst ----
    split_pad<<<((HD * FIN) + 255) / 256, 256, 0, stream>>>(w0, w0hi, w0lo, HD, FIN, FIN);
    split_pad<<<((HD * HIDP) + 255) / 256, 256, 0, stream>>>(w2, w2hi, w2lo, HD, HID, HIDP);
    split_pad<<<((NOUT * 512) + 255) / 256, 256, 0, stream>>>(w8, w8hi, w8lo, NOUT, 512, 512);
    fill_val<<<(Nn + 255) / 256, 256, 0, stream>>>((float*)cursor, 0.f, Nn);  // hist=0
    hist_k<<<edgeGrid, 256, 0, stream>>>(ei, cursor, E);
    scan_k<<<1, 1024, 0, stream>>>(cursor, base, Nn);
    copy_int<<<(Nn + 255) / 256, 256, 0, stream>>>(base, cursor, Nn);
    scatter_k<<<edgeGrid, 256, 0, stream>>>(ei, cursor, esrc, edst, eorg, E);

    // ---------- GAT layer 1 ----------
    gemm_mfma<0, false><<<gGemmL, 256, 0, stream>>>(x, nullptr, nullptr, w0hi, w0lo, nullptr,
                                                    h, Nn, HD, FIN);
    // w0hi slot is dead after gemm L1 -> reuse it for the Toeplitz frag table (18*512 ushorts)
    build_toeplitz<<<(18 * 512 + 255) / 256, 256, 0, stream>>>(w4, w6, w0hi);
    attn_dots<<<Nn, 256, 0, stream>>>(h, att_s0, att_d0, asrc, adst, Nn);
    node_aggregate<1><<<nodeWaveGrid, 256, 0, stream>>>(h, asrc, adst, base, esrc, b0,
                                                        nullptr, x1hi, x1lo, Nn);

    // ---------- GAT layer 2 (A pre-split: no conversion VALU in hot loop) ----------
    gemm_mfma<1, false><<<gGemmL, 256, 0, stream>>>(nullptr, x1hi, x1lo, w2hi, w2lo, nullptr,
                                                    h, Nn, HD, HIDP);
    attn_dots<<<Nn, 256, 0, stream>>>(h, att_s1, att_d1, asrc, adst, Nn);
    // layer-2 output written directly as bf16 hi/lo (consumed by MFMA conv)
    node_aggregate<1><<<nodeWaveGrid, 256, 0, stream>>>(h, asrc, adst, base, esrc, b2,
                                                        nullptr, x1hi, x1lo, Nn);

    // ---------- fused edge conv1+conv2+final linear (MFMA, 16 edges/block, dst-sorted) ----
    edge_fused<<<fusedGrid, 256, 0, stream>>>(x1hi, x1lo, esrc, edst, eorg, w0hi, b4, b6,
                                              w8hi, w8lo, b8, out, E);
}